// Round 3
// baseline (1051.073 us; speedup 1.0000x reference)
//
#include <hip/hip_runtime.h>

// ---------- bf16 helpers (manual, bit-level) ----------
__device__ __forceinline__ float bf_lo(unsigned u) { return __uint_as_float(u << 16); }
__device__ __forceinline__ float bf_hi(unsigned u) { return __uint_as_float(u & 0xffff0000u); }
__device__ __forceinline__ float bf1(unsigned short s) { return __uint_as_float(((unsigned)s) << 16); }
__device__ __forceinline__ unsigned short f2bf(float f) {
    unsigned u = __float_as_uint(f);
    u += 0x7fffu + ((u >> 16) & 1u);   // round-to-nearest-even
    return (unsigned short)(u >> 16);
}
__device__ __forceinline__ unsigned pack2(float a, float b) {
    return (unsigned)f2bf(a) | ((unsigned)f2bf(b) << 16);
}

// ---------- zeroing (never trust memset/poison state) ----------
__global__ void k_zero(int* __restrict__ p, int n) {
    int i = blockIdx.x * 256 + threadIdx.x;
    if (i < n) p[i] = 0;
}

// ---------- canary: pre-fill output with bf16 1.0 (diagnostic; overwritten by gemm2) ----------
__global__ void k_canary(unsigned short* __restrict__ p, int n) {
    int i = blockIdx.x * 256 + threadIdx.x;
    if (i < n) p[i] = 0x3F80;
}

// ---------- detect float dtype of x: flag=1 if words look like fp32 ----------
__global__ void k_detectf(const unsigned* __restrict__ x, int* __restrict__ flag) {
    int t = threadIdx.x;
    int c = 0;
    for (int i = t; i < 1024; i += 256) {
        unsigned e = (x[i] >> 23) & 0xffu;
        if (e >= 96u && e < 160u) c++;   // |v| roughly in [2^-31, 2^32]: fp32-plausible
    }
    __shared__ int s;
    if (t == 0) s = 0;
    __syncthreads();
    atomicAdd(&s, c);
    __syncthreads();
    if (t == 0) *flag = (s > 512) ? 1 : 0;
}

// ---------- detect edge_index width: flag=1 => int64 (odd words all zero) ----------
__global__ void k_detecte(const int* __restrict__ ei, int* __restrict__ flag) {
    int t = threadIdx.x;
    int nz = 0;
    for (int i = t; i < 2048; i += 256) nz |= ei[2 * i + 1];
    __shared__ int s;
    if (t == 0) s = 0;
    __syncthreads();
    if (nz) atomicOr(&s, 1);
    __syncthreads();
    if (t == 0) *flag = (s == 0) ? 1 : 0;
}

// ---------- dtype-normalizing copy: any float tensor -> bf16 ----------
__global__ void k_cvt(const void* __restrict__ in, unsigned short* __restrict__ out,
                      const int* __restrict__ flagf, int n) {
    int i = blockIdx.x * 256 + threadIdx.x;
    if (i >= n) return;
    if (*flagf) out[i] = f2bf(((const float*)in)[i]);
    else        out[i] = ((const unsigned short*)in)[i];
}

// ---------- CSR build ----------
__global__ void k_count(const int* __restrict__ ei, const int* __restrict__ flage,
                        int* __restrict__ cnt, int E, int N) {
    int e = blockIdx.x * 256 + threadIdx.x;
    if (e >= E) return;
    int st = *flage + 1;                      // 1 = int32 words, 2 = int64 words
    int c = ei[(size_t)st * (E + e)];
    if ((unsigned)c < (unsigned)N) atomicAdd(&cnt[c], 1);
}

__global__ void k_scan1(const int* __restrict__ cnt, int* __restrict__ ofs,
                        int* __restrict__ bsum, int N) {
    __shared__ int tmp[256];
    int t = threadIdx.x, i = blockIdx.x * 256 + t;
    int v = (i < N) ? cnt[i] : 0;
    tmp[t] = v; __syncthreads();
    for (int off = 1; off < 256; off <<= 1) {
        int xv = (t >= off) ? tmp[t - off] : 0;
        __syncthreads();
        tmp[t] += xv;
        __syncthreads();
    }
    if (i < N) ofs[i] = tmp[t] - v;
    if (t == 255) bsum[blockIdx.x] = tmp[255];
}

__global__ void k_scan2(int* __restrict__ bsum, int NB) {
    __shared__ int tmp[512];
    int t = threadIdx.x;
    int v = (t < NB) ? bsum[t] : 0;
    tmp[t] = v; __syncthreads();
    for (int off = 1; off < 512; off <<= 1) {
        int xv = (t >= off) ? tmp[t - off] : 0;
        __syncthreads();
        tmp[t] += xv;
        __syncthreads();
    }
    if (t < NB) bsum[t] = tmp[t] - v;
}

__global__ void k_scan3(const int* __restrict__ cnt, int* __restrict__ ofs,
                        const int* __restrict__ bsum, int* __restrict__ cursor,
                        float* __restrict__ dinv, int N) {
    int i = blockIdx.x * 256 + threadIdx.x;
    if (i >= N) return;
    int s = ofs[i] + bsum[i >> 8];
    ofs[i] = s;
    cursor[i] = s;
    int c = cnt[i]; if (c < 0) c = 0;
    dinv[i] = rsqrtf((float)(c + 1));         // +1 self-loop; NaN-proof
}

__global__ void k_fill(const int* __restrict__ ei, const int* __restrict__ flage,
                       int* __restrict__ cursor, int* __restrict__ csr, int E, int N) {
    int e = blockIdx.x * 256 + threadIdx.x;
    if (e >= E) return;
    int st = *flage + 1;
    int r = ei[(size_t)st * e];
    int c = ei[(size_t)st * (E + e)];
    if ((unsigned)c < (unsigned)N && (unsigned)r < (unsigned)N) {
        int pos = atomicAdd(&cursor[c], 1);
        if ((unsigned)pos < (unsigned)E) csr[pos] = r;
    }
}
// after k_fill, cursor[n] == end offset of node n

// ---------- layer-1 aggregation: s1 = D^-1/2 (A+I) D^-1/2 x  (64 feats, bf16 in, fp32 out) ----------
__global__ __launch_bounds__(256) void k_agg1(
        const unsigned short* __restrict__ x, const int* __restrict__ csr,
        const int* __restrict__ ofs, const int* __restrict__ endv,
        const float* __restrict__ dinv, float* __restrict__ s1, int N) {
    int node = blockIdx.x * 4 + (threadIdx.x >> 6);
    if (node >= N) return;
    int lane = threadIdx.x & 63;
    int beg = ofs[node], end = endv[node];
    float di = dinv[node];
    float acc = di * bf1(x[(size_t)node * 64 + lane]);   // self term
    for (int p = beg; p < end; ++p) {
        int r = csr[p];
        acc += dinv[r] * bf1(x[(size_t)r * 64 + lane]);
    }
    s1[(size_t)node * 64 + lane] = di * acc;
}

// ---------- GEMM1: h1 = bf16(relu(s1 @ W1 + b1)), fused BN stats (fp32) ----------
__global__ __launch_bounds__(256) void k_gemm1(
        const float* __restrict__ s1, const unsigned short* __restrict__ W1,
        const unsigned short* __restrict__ b1, unsigned short* __restrict__ h1,
        float* __restrict__ stats, int N) {
    __shared__ __align__(16) unsigned short sW[64 * 128];  // 16KB
    __shared__ __align__(16) float sA[8 * 64];             // 2KB
    __shared__ float sStat[256];                           // sum[0:128], sumsq[128:256]
    int t = threadIdx.x;
    {
        const uint2* wv = (const uint2*)W1;
        uint2* swv = (uint2*)sW;
        for (int i = t; i < 64 * 128 / 4; i += 256) swv[i] = wv[i];
    }
    int node0 = blockIdx.x * 8;
    if (node0 + 8 <= N) {
        const float4* av = (const float4*)(s1 + (size_t)node0 * 64);
        float4* sav = (float4*)sA;
        if (t < 128) sav[t] = av[t];
    } else {
        for (int i = t; i < 512; i += 256) {
            size_t g = (size_t)node0 * 64 + i;
            sA[i] = (g < (size_t)N * 64) ? s1[g] : 0.f;
        }
    }
    sStat[t] = 0.f;
    __syncthreads();

    int ln = t >> 5;            // node in block (0..7)
    int f0 = (t & 31) * 4;      // output feature base
    const unsigned* swu = (const unsigned*)sW;
    float a0 = 0, a1 = 0, a2 = 0, a3 = 0;
#pragma unroll 8
    for (int k = 0; k < 64; ++k) {
        float a = sA[ln * 64 + k];
        uint2 w = *(const uint2*)(swu + k * 64 + (f0 >> 1));
        a0 = fmaf(a, bf_lo(w.x), a0);
        a1 = fmaf(a, bf_hi(w.x), a1);
        a2 = fmaf(a, bf_lo(w.y), a2);
        a3 = fmaf(a, bf_hi(w.y), a3);
    }
    int node = node0 + ln;
    if (node < N) {
        float v0 = fmaxf(a0 + bf1(b1[f0 + 0]), 0.f);
        float v1 = fmaxf(a1 + bf1(b1[f0 + 1]), 0.f);
        float v2 = fmaxf(a2 + bf1(b1[f0 + 2]), 0.f);
        float v3 = fmaxf(a3 + bf1(b1[f0 + 3]), 0.f);
        uint2 o; o.x = pack2(v0, v1); o.y = pack2(v2, v3);
        *(uint2*)&h1[(size_t)node * 128 + f0] = o;
        atomicAdd(&sStat[f0 + 0], v0);  atomicAdd(&sStat[128 + f0 + 0], v0 * v0);
        atomicAdd(&sStat[f0 + 1], v1);  atomicAdd(&sStat[128 + f0 + 1], v1 * v1);
        atomicAdd(&sStat[f0 + 2], v2);  atomicAdd(&sStat[128 + f0 + 2], v2 * v2);
        atomicAdd(&sStat[f0 + 3], v3);  atomicAdd(&sStat[128 + f0 + 3], v3 * v3);
    }
    __syncthreads();
    atomicAdd(&stats[t], sStat[t]);
}

// ---------- BN finalize ----------
__global__ void k_bnfin(const float* __restrict__ stats,
                        const unsigned short* __restrict__ gamma,
                        const unsigned short* __restrict__ beta,
                        float* __restrict__ bnp, float invN) {
    int f = threadIdx.x;  // 128
    float mean = stats[f] * invN;
    float var = stats[128 + f] * invN - mean * mean;
    if (!(var >= 0.f)) var = 0.f;
    float sc = bf1(gamma[f]) * rsqrtf(var + 1e-5f);
    bnp[f] = sc;
    bnp[128 + f] = bf1(beta[f]) - mean * sc;
}

// ---------- BN apply + fold dinv: gb[n][f] = bf16(dinv[n]*(sc*h1+sh)) ----------
__global__ __launch_bounds__(256) void k_bnapply(
        const unsigned short* __restrict__ h1, const float* __restrict__ bnp,
        const float* __restrict__ dinv, unsigned short* __restrict__ gb, int N) {
    int idx = blockIdx.x * 256 + threadIdx.x;      // one per 4 elements
    if (idx >= N * 32) return;
    int n = idx >> 5;
    int f0 = (idx & 31) * 4;
    float di = dinv[n];
    uint2 h = *(const uint2*)&h1[(size_t)n * 128 + f0];
    float v0 = di * (bnp[f0 + 0] * bf_lo(h.x) + bnp[128 + f0 + 0]);
    float v1 = di * (bnp[f0 + 1] * bf_hi(h.x) + bnp[128 + f0 + 1]);
    float v2 = di * (bnp[f0 + 2] * bf_lo(h.y) + bnp[128 + f0 + 2]);
    float v3 = di * (bnp[f0 + 3] * bf_hi(h.y) + bnp[128 + f0 + 3]);
    uint2 o; o.x = pack2(v0, v1); o.y = pack2(v2, v3);
    *(uint2*)&gb[(size_t)n * 128 + f0] = o;
}

// ---------- layer-2 aggregation: s2 = bf16(dinv[n]*(sum gb[row] + gb[n]))  (128 feats) ----------
__global__ __launch_bounds__(256) void k_agg2(
        const unsigned short* __restrict__ gb, const int* __restrict__ csr,
        const int* __restrict__ ofs, const int* __restrict__ endv,
        const float* __restrict__ dinv, unsigned short* __restrict__ s2, int N) {
    int node = blockIdx.x * 4 + (threadIdx.x >> 6);
    if (node >= N) return;
    int lane = threadIdx.x & 63;
    const unsigned* g2 = (const unsigned*)gb;    // 2 bf16 per unsigned
    int beg = ofs[node], end = endv[node];
    float di = dinv[node];
    unsigned self = g2[(size_t)node * 64 + lane];
    float acc0 = bf_lo(self), acc1 = bf_hi(self);
    for (int p = beg; p < end; ++p) {
        int r = csr[p];
        unsigned v = g2[(size_t)r * 64 + lane];
        acc0 += bf_lo(v);
        acc1 += bf_hi(v);
    }
    ((unsigned*)s2)[(size_t)node * 64 + lane] = pack2(di * acc0, di * acc1);
}

// ---------- GEMM2: out = relu(s2 @ W2 + b2); output dtype follows flagf ----------
__global__ __launch_bounds__(256) void k_gemm2(
        const unsigned short* __restrict__ s2, const unsigned short* __restrict__ W2,
        const unsigned short* __restrict__ b2, void* __restrict__ outv,
        const int* __restrict__ flagf, int N) {
    __shared__ __align__(16) unsigned short sW[128 * 128];  // 32KB
    __shared__ __align__(16) unsigned short sA[8 * 128];    // 2KB
    int t = threadIdx.x;
    {
        const uint2* wv = (const uint2*)W2;
        uint2* swv = (uint2*)sW;
        for (int i = t; i < 128 * 128 / 4; i += 256) swv[i] = wv[i];
    }
    int node0 = blockIdx.x * 8;
    if (node0 + 8 <= N) {
        const uint2* av = (const uint2*)(s2 + (size_t)node0 * 128);
        ((uint2*)sA)[t] = av[t];                    // 256 * 8B = 2KB
    } else {
        for (int i = t; i < 1024; i += 256) {
            size_t g = (size_t)node0 * 128 + i;
            sA[i] = (g < (size_t)N * 128) ? s2[g] : 0;
        }
    }
    __syncthreads();

    int ln = t >> 5;
    int f0 = (t & 31) * 4;
    const unsigned* swu = (const unsigned*)sW;
    float a0 = 0, a1 = 0, a2 = 0, a3 = 0;
#pragma unroll 8
    for (int k = 0; k < 128; ++k) {
        float a = bf1(sA[ln * 128 + k]);
        uint2 w = *(const uint2*)(swu + k * 64 + (f0 >> 1));
        a0 = fmaf(a, bf_lo(w.x), a0);
        a1 = fmaf(a, bf_hi(w.x), a1);
        a2 = fmaf(a, bf_lo(w.y), a2);
        a3 = fmaf(a, bf_hi(w.y), a3);
    }
    int node = node0 + ln;
    if (node < N) {
        float v0 = fmaxf(a0 + bf1(b2[f0 + 0]), 0.f);
        float v1 = fmaxf(a1 + bf1(b2[f0 + 1]), 0.f);
        float v2 = fmaxf(a2 + bf1(b2[f0 + 2]), 0.f);
        float v3 = fmaxf(a3 + bf1(b2[f0 + 3]), 0.f);
        if (*flagf) {   // fp32 world -> fp32 output
            *(float4*)&((float*)outv)[(size_t)node * 128 + f0] = make_float4(v0, v1, v2, v3);
        } else {        // bf16 world -> bf16 output
            uint2 o; o.x = pack2(v0, v1); o.y = pack2(v2, v3);
            *(uint2*)&((unsigned short*)outv)[(size_t)node * 128 + f0] = o;
        }
    }
}

extern "C" void kernel_launch(void* const* d_in, const int* in_sizes, int n_in,
                              void* d_out, int out_size, void* d_ws, size_t ws_size,
                              hipStream_t stream) {
    const int N = in_sizes[0] / 64;   // 100000 (element counts are dtype-independent)
    const int E = in_sizes[1] / 2;    // 1600000
    const int nW1 = in_sizes[2], nb1 = in_sizes[3], ngm = in_sizes[4],
              nbt = in_sizes[5], nW2 = in_sizes[6], nb2 = in_sizes[7];

    const int* ei = (const int*)d_in[1];

    // workspace carve-up (~72 MB)
    char* w = (char*)d_ws;
    size_t off = 0;
    auto alloc = [&](size_t bytes) -> void* {
        void* p = w + off;
        off = (off + bytes + 255) & ~(size_t)255;
        return p;
    };
    int*   cnt    = (int*)alloc((size_t)N * 4);
    int*   ofs    = (int*)alloc((size_t)N * 4);
    int*   bsum   = (int*)alloc(512 * 4);
    int*   flagf  = (int*)alloc(256);
    int*   flage  = (int*)alloc(256);
    int*   cursor = (int*)alloc((size_t)N * 4);
    int*   csr    = (int*)alloc((size_t)E * 4);
    float* dinv   = (float*)alloc((size_t)N * 4);
    float* stats  = (float*)alloc(512 * 4);                       // sums[256] + bnp[256]
    unsigned short* xb = (unsigned short*)alloc((size_t)N * 64 * 2);   // 12.8MB
    unsigned short* wb = (unsigned short*)alloc((size_t)32768 * 2);    // all params, bf16
    float* s1 = (float*)alloc((size_t)N * 64 * 4);                // 25.6MB; reused as gb (bf16 N*128)
    unsigned short* h1 = (unsigned short*)alloc((size_t)N * 128 * 2);  // 25.6MB; reused as s2
    unsigned short* gb = (unsigned short*)s1;
    unsigned short* s2 = h1;

    unsigned short* W1b = wb;
    unsigned short* b1b = W1b + nW1;
    unsigned short* gmb = b1b + nb1;
    unsigned short* btb = gmb + ngm;
    unsigned short* W2b = btb + nbt;
    unsigned short* b2b = W2b + nW2;

    const int NB = (N + 255) / 256;  // 391 (<=512 for single-block scan2)

    k_zero   <<<NB, 256, 0, stream>>>(cnt, N);
    k_zero   <<<1, 256, 0, stream>>>((int*)stats, 256);
    k_canary <<<(out_size + 255) / 256, 256, 0, stream>>>((unsigned short*)d_out, out_size);
    k_detectf<<<1, 256, 0, stream>>>((const unsigned*)d_in[0], flagf);
    k_detecte<<<1, 256, 0, stream>>>(ei, flage);

    k_cvt <<<(N * 64 + 255) / 256, 256, 0, stream>>>(d_in[0], xb, flagf, N * 64);
    k_cvt <<<(nW1 + 255) / 256, 256, 0, stream>>>(d_in[2], W1b, flagf, nW1);
    k_cvt <<<(nb1 + 255) / 256, 256, 0, stream>>>(d_in[3], b1b, flagf, nb1);
    k_cvt <<<(ngm + 255) / 256, 256, 0, stream>>>(d_in[4], gmb, flagf, ngm);
    k_cvt <<<(nbt + 255) / 256, 256, 0, stream>>>(d_in[5], btb, flagf, nbt);
    k_cvt <<<(nW2 + 255) / 256, 256, 0, stream>>>(d_in[6], W2b, flagf, nW2);
    k_cvt <<<(nb2 + 255) / 256, 256, 0, stream>>>(d_in[7], b2b, flagf, nb2);

    k_count <<<(E + 255) / 256, 256, 0, stream>>>(ei, flage, cnt, E, N);
    k_scan1 <<<NB, 256, 0, stream>>>(cnt, ofs, bsum, N);
    k_scan2 <<<1, 512, 0, stream>>>(bsum, NB);
    k_scan3 <<<NB, 256, 0, stream>>>(cnt, ofs, bsum, cursor, dinv, N);
    k_fill  <<<(E + 255) / 256, 256, 0, stream>>>(ei, flage, cursor, csr, E, N);

    k_agg1  <<<(N + 3) / 4, 256, 0, stream>>>(xb, csr, ofs, cursor, dinv, s1, N);
    k_gemm1 <<<(N + 7) / 8, 256, 0, stream>>>(s1, W1b, b1b, h1, stats, N);
    k_bnfin <<<1, 128, 0, stream>>>(stats, gmb, btb, stats + 256, 1.0f / (float)N);
    k_bnapply<<<((size_t)N * 32 + 255) / 256, 256, 0, stream>>>(h1, stats + 256, dinv, gb, N);
    k_agg2  <<<(N + 3) / 4, 256, 0, stream>>>(gb, csr, ofs, cursor, dinv, s2, N);
    k_gemm2 <<<(N + 7) / 8, 256, 0, stream>>>(s2, W2b, b2b, d_out, flagf, N);
}

// Round 4
// 664.740 us; speedup vs baseline: 1.5812x; 1.5812x over previous
//
#include <hip/hip_runtime.h>

// ---------- bf16 helpers (manual, bit-level) ----------
__device__ __forceinline__ float bf_lo(unsigned u) { return __uint_as_float(u << 16); }
__device__ __forceinline__ float bf_hi(unsigned u) { return __uint_as_float(u & 0xffff0000u); }
__device__ __forceinline__ float bf1(unsigned short s) { return __uint_as_float(((unsigned)s) << 16); }
__device__ __forceinline__ unsigned short f2bf(float f) {
    unsigned u = __float_as_uint(f);
    u += 0x7fffu + ((u >> 16) & 1u);   // round-to-nearest-even
    return (unsigned short)(u >> 16);
}
__device__ __forceinline__ unsigned pack2(float a, float b) {
    return (unsigned)f2bf(a) | ((unsigned)f2bf(b) << 16);
}

// ---------- zeroing (never trust memset/poison state) ----------
__global__ void k_zero(int* __restrict__ p, int n) {
    int i = blockIdx.x * 256 + threadIdx.x;
    if (i < n) p[i] = 0;
}

// ---------- detect float dtype of x: flag=1 if words look like fp32 ----------
__global__ void k_detectf(const unsigned* __restrict__ x, int* __restrict__ flag) {
    int t = threadIdx.x;
    int c = 0;
    for (int i = t; i < 1024; i += 256) {
        unsigned e = (x[i] >> 23) & 0xffu;
        if (e >= 96u && e < 160u) c++;   // fp32-plausible exponent
    }
    __shared__ int s;
    if (t == 0) s = 0;
    __syncthreads();
    atomicAdd(&s, c);
    __syncthreads();
    if (t == 0) *flag = (s > 512) ? 1 : 0;
}

// ---------- detect edge_index width: flag=1 => int64 (odd words all zero) ----------
__global__ void k_detecte(const int* __restrict__ ei, int* __restrict__ flag) {
    int t = threadIdx.x;
    int nz = 0;
    for (int i = t; i < 2048; i += 256) nz |= ei[2 * i + 1];
    __shared__ int s;
    if (t == 0) s = 0;
    __syncthreads();
    if (nz) atomicOr(&s, 1);
    __syncthreads();
    if (t == 0) *flag = (s == 0) ? 1 : 0;
}

// ---------- dtype-normalizing copy: any float tensor -> bf16 ----------
__global__ void k_cvt(const void* __restrict__ in, unsigned short* __restrict__ out,
                      const int* __restrict__ flagf, int n) {
    int i = blockIdx.x * 256 + threadIdx.x;
    if (i >= n) return;
    if (*flagf) out[i] = f2bf(((const float*)in)[i]);
    else        out[i] = ((const unsigned short*)in)[i];
}

// ---------- x prep: xs[n][f] = bf16(dinv[n] * x[n][f]) (removes per-edge dinv load) ----------
__global__ __launch_bounds__(256) void k_prep(
        const void* __restrict__ x, const float* __restrict__ dinv,
        const int* __restrict__ flagf, unsigned short* __restrict__ xs, int NF) {
    int i = blockIdx.x * 256 + threadIdx.x;
    if (i >= NF) return;
    int n = i >> 6;
    float v = *flagf ? ((const float*)x)[i] : bf1(((const unsigned short*)x)[i]);
    xs[i] = f2bf(dinv[n] * v);
}

// ---------- CSR build ----------
__global__ void k_count(const int* __restrict__ ei, const int* __restrict__ flage,
                        int* __restrict__ cnt, int E, int N) {
    int e = blockIdx.x * 256 + threadIdx.x;
    if (e >= E) return;
    int st = *flage + 1;                      // 1 = int32 words, 2 = int64 words
    int c = ei[(size_t)st * (E + e)];
    if ((unsigned)c < (unsigned)N) atomicAdd(&cnt[c], 1);
}

__global__ void k_scan1(const int* __restrict__ cnt, int* __restrict__ ofs,
                        int* __restrict__ bsum, int N) {
    __shared__ int tmp[256];
    int t = threadIdx.x, i = blockIdx.x * 256 + t;
    int v = (i < N) ? cnt[i] : 0;
    tmp[t] = v; __syncthreads();
    for (int off = 1; off < 256; off <<= 1) {
        int xv = (t >= off) ? tmp[t - off] : 0;
        __syncthreads();
        tmp[t] += xv;
        __syncthreads();
    }
    if (i < N) ofs[i] = tmp[t] - v;
    if (t == 255) bsum[blockIdx.x] = tmp[255];
}

__global__ void k_scan2(int* __restrict__ bsum, int NB) {
    __shared__ int tmp[512];
    int t = threadIdx.x;
    int v = (t < NB) ? bsum[t] : 0;
    tmp[t] = v; __syncthreads();
    for (int off = 1; off < 512; off <<= 1) {
        int xv = (t >= off) ? tmp[t - off] : 0;
        __syncthreads();
        tmp[t] += xv;
        __syncthreads();
    }
    if (t < NB) bsum[t] = tmp[t] - v;
}

__global__ void k_scan3(const int* __restrict__ cnt, int* __restrict__ ofs,
                        const int* __restrict__ bsum, int* __restrict__ cursor,
                        float* __restrict__ dinv, int N) {
    int i = blockIdx.x * 256 + threadIdx.x;
    if (i >= N) return;
    int s = ofs[i] + bsum[i >> 8];
    ofs[i] = s;
    cursor[i] = s;
    int c = cnt[i]; if (c < 0) c = 0;
    dinv[i] = rsqrtf((float)(c + 1));         // +1 self-loop; NaN-proof
}

__global__ void k_fill(const int* __restrict__ ei, const int* __restrict__ flage,
                       int* __restrict__ cursor, int* __restrict__ csr, int E, int N) {
    int e = blockIdx.x * 256 + threadIdx.x;
    if (e >= E) return;
    int st = *flage + 1;
    int r = ei[(size_t)st * e];
    int c = ei[(size_t)st * (E + e)];
    if ((unsigned)c < (unsigned)N && (unsigned)r < (unsigned)N) {
        int pos = atomicAdd(&cursor[c], 1);
        if ((unsigned)pos < (unsigned)E) csr[pos] = r;
    }
}
// after k_fill, cursor[n] == end offset of node n

// ---------- layer-1 aggregation: s1[n] = dinv[n] * (xs[n] + sum_{r in nbrs} xs[r]) ----------
__global__ __launch_bounds__(256) void k_agg1(
        const unsigned short* __restrict__ xs, const int* __restrict__ csr,
        const int* __restrict__ ofs, const int* __restrict__ endv,
        const float* __restrict__ dinv, float* __restrict__ s1, int N) {
    int node = blockIdx.x * 4 + (threadIdx.x >> 6);
    if (node >= N) return;
    int lane = threadIdx.x & 63;
    int beg = ofs[node], end = endv[node];
    float acc = bf1(xs[(size_t)node * 64 + lane]);   // self term (pre-scaled)
    int p = beg;
    for (; p + 3 < end; p += 4) {                    // 4-deep latency pipeline
        int r0 = csr[p], r1 = csr[p + 1], r2 = csr[p + 2], r3 = csr[p + 3];
        float v0 = bf1(xs[(size_t)r0 * 64 + lane]);
        float v1 = bf1(xs[(size_t)r1 * 64 + lane]);
        float v2 = bf1(xs[(size_t)r2 * 64 + lane]);
        float v3 = bf1(xs[(size_t)r3 * 64 + lane]);
        acc += v0 + v1 + v2 + v3;
    }
    for (; p < end; ++p)
        acc += bf1(xs[(size_t)csr[p] * 64 + lane]);
    s1[(size_t)node * 64 + lane] = dinv[node] * acc;
}

// ---------- GEMM1: h1 = bf16(relu(s1 @ W1 + b1)) (no stats here!) ----------
__global__ __launch_bounds__(256) void k_gemm1(
        const float* __restrict__ s1, const unsigned short* __restrict__ W1,
        const unsigned short* __restrict__ b1, unsigned short* __restrict__ h1, int N) {
    __shared__ __align__(16) unsigned short sW[64 * 128];  // 16KB
    __shared__ __align__(16) float sA[8 * 64];             // 2KB
    int t = threadIdx.x;
    {
        const uint2* wv = (const uint2*)W1;
        uint2* swv = (uint2*)sW;
        for (int i = t; i < 64 * 128 / 4; i += 256) swv[i] = wv[i];
    }
    int node0 = blockIdx.x * 8;
    if (node0 + 8 <= N) {
        const float4* av = (const float4*)(s1 + (size_t)node0 * 64);
        float4* sav = (float4*)sA;
        if (t < 128) sav[t] = av[t];
    } else {
        for (int i = t; i < 512; i += 256) {
            size_t g = (size_t)node0 * 64 + i;
            sA[i] = (g < (size_t)N * 64) ? s1[g] : 0.f;
        }
    }
    __syncthreads();

    int ln = t >> 5;            // node in block (0..7)
    int f0 = (t & 31) * 4;      // output feature base
    const unsigned* swu = (const unsigned*)sW;
    float a0 = 0, a1 = 0, a2 = 0, a3 = 0;
#pragma unroll 8
    for (int k = 0; k < 64; ++k) {
        float a = sA[ln * 64 + k];
        uint2 w = *(const uint2*)(swu + k * 64 + (f0 >> 1));
        a0 = fmaf(a, bf_lo(w.x), a0);
        a1 = fmaf(a, bf_hi(w.x), a1);
        a2 = fmaf(a, bf_lo(w.y), a2);
        a3 = fmaf(a, bf_hi(w.y), a3);
    }
    int node = node0 + ln;
    if (node < N) {
        float v0 = fmaxf(a0 + bf1(b1[f0 + 0]), 0.f);
        float v1 = fmaxf(a1 + bf1(b1[f0 + 1]), 0.f);
        float v2 = fmaxf(a2 + bf1(b1[f0 + 2]), 0.f);
        float v3 = fmaxf(a3 + bf1(b1[f0 + 3]), 0.f);
        uint2 o; o.x = pack2(v0, v1); o.y = pack2(v2, v3);
        *(uint2*)&h1[(size_t)node * 128 + f0] = o;
    }
}

// ---------- BN stats: 256 blocks, register accumulation, LDS reduce, sparse atomics ----------
__global__ __launch_bounds__(256) void k_bnstat(
        const unsigned short* __restrict__ h1, float* __restrict__ stats, int N) {
    __shared__ float sS[256], sQ[256];
    int t = threadIdx.x;
    int f = t & 127;
    int half = t >> 7;                 // 0 or 1: interleaved node pairs
    float s = 0.f, q = 0.f;
    for (int n = blockIdx.x * 2 + half; n < N; n += 512) {
        float v = bf1(h1[(size_t)n * 128 + f]);
        s += v; q = fmaf(v, v, q);
    }
    sS[t] = s; sQ[t] = q;
    __syncthreads();
    if (t < 128) {
        atomicAdd(&stats[f],       sS[t] + sS[t + 128]);
        atomicAdd(&stats[128 + f], sQ[t] + sQ[t + 128]);
    }
}

// ---------- BN finalize ----------
__global__ void k_bnfin(const float* __restrict__ stats,
                        const unsigned short* __restrict__ gamma,
                        const unsigned short* __restrict__ beta,
                        float* __restrict__ bnp, float invN) {
    int f = threadIdx.x;  // 128
    float mean = stats[f] * invN;
    float var = stats[128 + f] * invN - mean * mean;
    if (!(var >= 0.f)) var = 0.f;
    float sc = bf1(gamma[f]) * rsqrtf(var + 1e-5f);
    bnp[f] = sc;
    bnp[128 + f] = bf1(beta[f]) - mean * sc;
}

// ---------- BN apply + fold dinv: gb[n][f] = bf16(dinv[n]*(sc*h1+sh)) ----------
__global__ __launch_bounds__(256) void k_bnapply(
        const unsigned short* __restrict__ h1, const float* __restrict__ bnp,
        const float* __restrict__ dinv, unsigned short* __restrict__ gb, int N) {
    int idx = blockIdx.x * 256 + threadIdx.x;      // one per 4 elements
    if (idx >= N * 32) return;
    int n = idx >> 5;
    int f0 = (idx & 31) * 4;
    float di = dinv[n];
    uint2 h = *(const uint2*)&h1[(size_t)n * 128 + f0];
    float v0 = di * (bnp[f0 + 0] * bf_lo(h.x) + bnp[128 + f0 + 0]);
    float v1 = di * (bnp[f0 + 1] * bf_hi(h.x) + bnp[128 + f0 + 1]);
    float v2 = di * (bnp[f0 + 2] * bf_lo(h.y) + bnp[128 + f0 + 2]);
    float v3 = di * (bnp[f0 + 3] * bf_hi(h.y) + bnp[128 + f0 + 3]);
    uint2 o; o.x = pack2(v0, v1); o.y = pack2(v2, v3);
    *(uint2*)&gb[(size_t)n * 128 + f0] = o;
}

// ---------- layer-2 aggregation: s2 = bf16(dinv[n]*(sum gb[row] + gb[n]))  (128 feats) ----------
__global__ __launch_bounds__(256) void k_agg2(
        const unsigned short* __restrict__ gb, const int* __restrict__ csr,
        const int* __restrict__ ofs, const int* __restrict__ endv,
        const float* __restrict__ dinv, unsigned short* __restrict__ s2, int N) {
    int node = blockIdx.x * 4 + (threadIdx.x >> 6);
    if (node >= N) return;
    int lane = threadIdx.x & 63;
    const unsigned* g2 = (const unsigned*)gb;    // 2 bf16 per unsigned
    int beg = ofs[node], end = endv[node];
    float di = dinv[node];
    unsigned self = g2[(size_t)node * 64 + lane];
    float acc0 = bf_lo(self), acc1 = bf_hi(self);
    int p = beg;
    for (; p + 3 < end; p += 4) {                // 4-deep latency pipeline
        int r0 = csr[p], r1 = csr[p + 1], r2 = csr[p + 2], r3 = csr[p + 3];
        unsigned u0 = g2[(size_t)r0 * 64 + lane];
        unsigned u1 = g2[(size_t)r1 * 64 + lane];
        unsigned u2 = g2[(size_t)r2 * 64 + lane];
        unsigned u3 = g2[(size_t)r3 * 64 + lane];
        acc0 += bf_lo(u0) + bf_lo(u1) + bf_lo(u2) + bf_lo(u3);
        acc1 += bf_hi(u0) + bf_hi(u1) + bf_hi(u2) + bf_hi(u3);
    }
    for (; p < end; ++p) {
        unsigned v = g2[(size_t)csr[p] * 64 + lane];
        acc0 += bf_lo(v);
        acc1 += bf_hi(v);
    }
    ((unsigned*)s2)[(size_t)node * 64 + lane] = pack2(di * acc0, di * acc1);
}

// ---------- GEMM2: out = relu(s2 @ W2 + b2); output dtype follows flagf ----------
__global__ __launch_bounds__(256) void k_gemm2(
        const unsigned short* __restrict__ s2, const unsigned short* __restrict__ W2,
        const unsigned short* __restrict__ b2, void* __restrict__ outv,
        const int* __restrict__ flagf, int N) {
    __shared__ __align__(16) unsigned short sW[128 * 128];  // 32KB
    __shared__ __align__(16) unsigned short sA[8 * 128];    // 2KB
    int t = threadIdx.x;
    {
        const uint2* wv = (const uint2*)W2;
        uint2* swv = (uint2*)sW;
        for (int i = t; i < 128 * 128 / 4; i += 256) swv[i] = wv[i];
    }
    int node0 = blockIdx.x * 8;
    if (node0 + 8 <= N) {
        const uint2* av = (const uint2*)(s2 + (size_t)node0 * 128);
        ((uint2*)sA)[t] = av[t];
    } else {
        for (int i = t; i < 1024; i += 256) {
            size_t g = (size_t)node0 * 128 + i;
            sA[i] = (g < (size_t)N * 128) ? s2[g] : 0;
        }
    }
    __syncthreads();

    int ln = t >> 5;
    int f0 = (t & 31) * 4;
    const unsigned* swu = (const unsigned*)sW;
    float a0 = 0, a1 = 0, a2 = 0, a3 = 0;
#pragma unroll 8
    for (int k = 0; k < 128; ++k) {
        float a = bf1(sA[ln * 128 + k]);
        uint2 w = *(const uint2*)(swu + k * 64 + (f0 >> 1));
        a0 = fmaf(a, bf_lo(w.x), a0);
        a1 = fmaf(a, bf_hi(w.x), a1);
        a2 = fmaf(a, bf_lo(w.y), a2);
        a3 = fmaf(a, bf_hi(w.y), a3);
    }
    int node = node0 + ln;
    if (node < N) {
        float v0 = fmaxf(a0 + bf1(b2[f0 + 0]), 0.f);
        float v1 = fmaxf(a1 + bf1(b2[f0 + 1]), 0.f);
        float v2 = fmaxf(a2 + bf1(b2[f0 + 2]), 0.f);
        float v3 = fmaxf(a3 + bf1(b2[f0 + 3]), 0.f);
        if (*flagf) {
            *(float4*)&((float*)outv)[(size_t)node * 128 + f0] = make_float4(v0, v1, v2, v3);
        } else {
            uint2 o; o.x = pack2(v0, v1); o.y = pack2(v2, v3);
            *(uint2*)&((unsigned short*)outv)[(size_t)node * 128 + f0] = o;
        }
    }
}

extern "C" void kernel_launch(void* const* d_in, const int* in_sizes, int n_in,
                              void* d_out, int out_size, void* d_ws, size_t ws_size,
                              hipStream_t stream) {
    const int N = in_sizes[0] / 64;   // 100000
    const int E = in_sizes[1] / 2;    // 1600000
    const int nW1 = in_sizes[2], nb1 = in_sizes[3], ngm = in_sizes[4],
              nbt = in_sizes[5], nW2 = in_sizes[6], nb2 = in_sizes[7];

    const int* ei = (const int*)d_in[1];

    // workspace carve-up (~72 MB)
    char* w = (char*)d_ws;
    size_t off = 0;
    auto alloc = [&](size_t bytes) -> void* {
        void* p = w + off;
        off = (off + bytes + 255) & ~(size_t)255;
        return p;
    };
    int*   cnt    = (int*)alloc((size_t)N * 4);
    int*   ofs    = (int*)alloc((size_t)N * 4);
    int*   bsum   = (int*)alloc(512 * 4);
    int*   flagf  = (int*)alloc(256);
    int*   flage  = (int*)alloc(256);
    int*   cursor = (int*)alloc((size_t)N * 4);
    int*   csr    = (int*)alloc((size_t)E * 4);
    float* dinv   = (float*)alloc((size_t)N * 4);
    float* stats  = (float*)alloc(512 * 4);                       // sums[256] + bnp[256]
    unsigned short* xs = (unsigned short*)alloc((size_t)N * 64 * 2);   // 12.8MB, dinv-prescaled x
    unsigned short* wb = (unsigned short*)alloc((size_t)32768 * 2);    // all params, bf16
    float* s1 = (float*)alloc((size_t)N * 64 * 4);                // 25.6MB; reused as gb (bf16 N*128)
    unsigned short* h1 = (unsigned short*)alloc((size_t)N * 128 * 2);  // 25.6MB; reused as s2
    unsigned short* gb = (unsigned short*)s1;
    unsigned short* s2 = h1;

    unsigned short* W1b = wb;
    unsigned short* b1b = W1b + nW1;
    unsigned short* gmb = b1b + nb1;
    unsigned short* btb = gmb + ngm;
    unsigned short* W2b = btb + nbt;
    unsigned short* b2b = W2b + nW2;

    const int NB = (N + 255) / 256;  // 391 (<=512 for single-block scan2)

    k_zero   <<<NB, 256, 0, stream>>>(cnt, N);
    k_zero   <<<1, 256, 0, stream>>>((int*)stats, 256);
    k_detectf<<<1, 256, 0, stream>>>((const unsigned*)d_in[0], flagf);
    k_detecte<<<1, 256, 0, stream>>>(ei, flage);

    k_cvt <<<(nW1 + 255) / 256, 256, 0, stream>>>(d_in[2], W1b, flagf, nW1);
    k_cvt <<<(nb1 + 255) / 256, 256, 0, stream>>>(d_in[3], b1b, flagf, nb1);
    k_cvt <<<(ngm + 255) / 256, 256, 0, stream>>>(d_in[4], gmb, flagf, ngm);
    k_cvt <<<(nbt + 255) / 256, 256, 0, stream>>>(d_in[5], btb, flagf, nbt);
    k_cvt <<<(nW2 + 255) / 256, 256, 0, stream>>>(d_in[6], W2b, flagf, nW2);
    k_cvt <<<(nb2 + 255) / 256, 256, 0, stream>>>(d_in[7], b2b, flagf, nb2);

    k_count <<<(E + 255) / 256, 256, 0, stream>>>(ei, flage, cnt, E, N);
    k_scan1 <<<NB, 256, 0, stream>>>(cnt, ofs, bsum, N);
    k_scan2 <<<1, 512, 0, stream>>>(bsum, NB);
    k_scan3 <<<NB, 256, 0, stream>>>(cnt, ofs, bsum, cursor, dinv, N);
    k_fill  <<<(E + 255) / 256, 256, 0, stream>>>(ei, flage, cursor, csr, E, N);

    k_prep  <<<(N * 64 + 255) / 256, 256, 0, stream>>>(d_in[0], dinv, flagf, xs, N * 64);
    k_agg1  <<<(N + 3) / 4, 256, 0, stream>>>(xs, csr, ofs, cursor, dinv, s1, N);
    k_gemm1 <<<(N + 7) / 8, 256, 0, stream>>>(s1, W1b, b1b, h1, N);
    k_bnstat<<<256, 256, 0, stream>>>(h1, stats, N);
    k_bnfin <<<1, 128, 0, stream>>>(stats, gmb, btb, stats + 256, 1.0f / (float)N);
    k_bnapply<<<((size_t)N * 32 + 255) / 256, 256, 0, stream>>>(h1, stats + 256, dinv, gb, N);
    k_agg2  <<<(N + 3) / 4, 256, 0, stream>>>(gb, csr, ofs, cursor, dinv, s2, N);
    k_gemm2 <<<(N + 7) / 8, 256, 0, stream>>>(s2, W2b, b2b, d_out, flagf, N);
}

// Round 5
// 511.824 us; speedup vs baseline: 2.0536x; 1.2988x over previous
//
#include <hip/hip_runtime.h>

#define BSZ_LG 9
#define BSZ 512            // nodes per destination bucket

// ---------- bf16 helpers (manual, bit-level) ----------
__device__ __forceinline__ float bf_lo(unsigned u) { return __uint_as_float(u << 16); }
__device__ __forceinline__ float bf_hi(unsigned u) { return __uint_as_float(u & 0xffff0000u); }
__device__ __forceinline__ float bf1(unsigned short s) { return __uint_as_float(((unsigned)s) << 16); }
__device__ __forceinline__ unsigned short f2bf(float f) {
    unsigned u = __float_as_uint(f);
    u += 0x7fffu + ((u >> 16) & 1u);   // round-to-nearest-even
    return (unsigned short)(u >> 16);
}
__device__ __forceinline__ unsigned pack2(float a, float b) {
    return (unsigned)f2bf(a) | ((unsigned)f2bf(b) << 16);
}

// ---------- zeroing (never trust memset/poison state) ----------
__global__ void k_zero(int* __restrict__ p, int n) {
    int i = blockIdx.x * 256 + threadIdx.x;
    if (i < n) p[i] = 0;
}

// ---------- detect float dtype of x: flag=1 if words look like fp32 ----------
__global__ void k_detectf(const unsigned* __restrict__ x, int* __restrict__ flag) {
    int t = threadIdx.x;
    int c = 0;
    for (int i = t; i < 1024; i += 256) {
        unsigned e = (x[i] >> 23) & 0xffu;
        if (e >= 96u && e < 160u) c++;   // fp32-plausible exponent
    }
    __shared__ int s;
    if (t == 0) s = 0;
    __syncthreads();
    atomicAdd(&s, c);
    __syncthreads();
    if (t == 0) *flag = (s > 512) ? 1 : 0;
}

// ---------- detect edge_index width: flag=1 => int64 (odd words all zero) ----------
__global__ void k_detecte(const int* __restrict__ ei, int* __restrict__ flag) {
    int t = threadIdx.x;
    int nz = 0;
    for (int i = t; i < 2048; i += 256) nz |= ei[2 * i + 1];
    __shared__ int s;
    if (t == 0) s = 0;
    __syncthreads();
    if (nz) atomicOr(&s, 1);
    __syncthreads();
    if (t == 0) *flag = (s == 0) ? 1 : 0;
}

// ---------- dtype-normalizing copy: any float tensor -> bf16 ----------
__global__ void k_cvt(const void* __restrict__ in, unsigned short* __restrict__ out,
                      const int* __restrict__ flagf, int n) {
    int i = blockIdx.x * 256 + threadIdx.x;
    if (i >= n) return;
    if (*flagf) out[i] = f2bf(((const float*)in)[i]);
    else        out[i] = ((const unsigned short*)in)[i];
}

// ---------- x prep: xs[n][f] = bf16(dinv[n] * x[n][f]) ----------
__global__ __launch_bounds__(256) void k_prep(
        const void* __restrict__ x, const float* __restrict__ dinv,
        const int* __restrict__ flagf, unsigned short* __restrict__ xs, int NF) {
    int i = blockIdx.x * 256 + threadIdx.x;
    if (i >= NF) return;
    int n = i >> 6;
    float v = *flagf ? ((const float*)x)[i] : bf1(((const unsigned short*)x)[i]);
    xs[i] = f2bf(dinv[n] * v);
}

// ================= bucketed CSR build (line-dense writes) =================
// Phase A: per-bucket edge counts (LDS histogram, sparse global atomics)
__global__ __launch_bounds__(256) void k_binA(
        const int* __restrict__ ei, const int* __restrict__ flage,
        int* __restrict__ bcnt, int E, int N, int NBUCK) {
    __shared__ int hist[256];
    int t = threadIdx.x;
    hist[t] = 0;
    __syncthreads();
    int st = *flage + 1;
    int base = blockIdx.x * 4096 + t;
#pragma unroll
    for (int i = 0; i < 16; ++i) {
        int e = base + i * 256;
        if (e < E) {
            int r = ei[(size_t)st * e];
            int c = ei[(size_t)st * (E + e)];
            if ((unsigned)r < (unsigned)N && (unsigned)c < (unsigned)N)
                atomicAdd(&hist[c >> BSZ_LG], 1);
        }
    }
    __syncthreads();
    if (t < NBUCK && hist[t] > 0) atomicAdd(&bcnt[t], hist[t]);
}

// scan bucket counts -> bofs[NBUCK+1], init bcur
__global__ void k_bscan(const int* __restrict__ bcnt, int* __restrict__ bofs,
                        int* __restrict__ bcur, int NBUCK) {
    __shared__ int tmp[256];
    int t = threadIdx.x;
    int v = (t < NBUCK) ? bcnt[t] : 0;
    tmp[t] = v; __syncthreads();
    for (int off = 1; off < 256; off <<= 1) {
        int xv = (t >= off) ? tmp[t - off] : 0;
        __syncthreads();
        tmp[t] += xv;
        __syncthreads();
    }
    if (t < NBUCK) {
        int ex = tmp[t] - v;
        bofs[t] = ex;
        bcur[t] = ex;
        if (t == NBUCK - 1) bofs[NBUCK] = tmp[t];
    }
}

// Phase B: scatter edges into bucket-contiguous bins via LDS reorder.
// bins[] entry = (r << BSZ_LG) | (c & (BSZ-1)), grouped by bucket.
__global__ __launch_bounds__(256) void k_binB(
        const int* __restrict__ ei, const int* __restrict__ flage,
        int* __restrict__ bcur, unsigned* __restrict__ bins, int E, int N, int NBUCK) {
    __shared__ int hist[256], hincl[256], hofs[256], loc[256], gbase[256];
    __shared__ unsigned stage[4096];
    __shared__ unsigned char bseg[4096];
    int t = threadIdx.x;
    hist[t] = 0; loc[t] = 0;
    __syncthreads();
    int st = *flage + 1;
    int base = blockIdx.x * 4096 + t;
    int bs[16]; unsigned vs[16];
#pragma unroll
    for (int i = 0; i < 16; ++i) {
        int e = base + i * 256;
        bs[i] = -1; vs[i] = 0;
        if (e < E) {
            int r = ei[(size_t)st * e];
            int c = ei[(size_t)st * (E + e)];
            if ((unsigned)r < (unsigned)N && (unsigned)c < (unsigned)N) {
                bs[i] = c >> BSZ_LG;
                vs[i] = ((unsigned)r << BSZ_LG) | (unsigned)(c & (BSZ - 1));
                atomicAdd(&hist[bs[i]], 1);
            }
        }
    }
    __syncthreads();
    hincl[t] = hist[t];
    __syncthreads();
    for (int off = 1; off < 256; off <<= 1) {
        int xv = (t >= off) ? hincl[t - off] : 0;
        __syncthreads();
        hincl[t] += xv;
        __syncthreads();
    }
    hofs[t] = hincl[t] - hist[t];
    if (t < NBUCK && hist[t] > 0) gbase[t] = atomicAdd(&bcur[t], hist[t]);
    __syncthreads();
#pragma unroll
    for (int i = 0; i < 16; ++i) {
        if (bs[i] >= 0) {
            int l = atomicAdd(&loc[bs[i]], 1);
            int pos = hofs[bs[i]] + l;
            stage[pos] = vs[i];
            bseg[pos] = (unsigned char)bs[i];
        }
    }
    __syncthreads();
    int total = hincl[255];
    for (int j = t; j < total; j += 256) {
        int b = bseg[j];
        bins[gbase[b] + (j - hofs[b])] = stage[j];   // bucket-contiguous runs
    }
}

// Phase C: one block per bucket — LDS count+scan (no global atomics),
// writes ofs/end/dinv, scatters csr within an L2-resident 2KB*16 span.
__global__ __launch_bounds__(512) void k_csr(
        const unsigned* __restrict__ bins, const int* __restrict__ bofs,
        int* __restrict__ csr, int* __restrict__ ofs, int* __restrict__ endv,
        float* __restrict__ dinv, int N) {
    __shared__ int tmp[BSZ];
    __shared__ int cur[BSZ];
    int b = blockIdx.x, t = threadIdx.x;
    int eb = bofs[b], ee = bofs[b + 1];
    tmp[t] = 0;
    __syncthreads();
    for (int p = eb + t; p < ee; p += BSZ)
        atomicAdd(&tmp[bins[p] & (BSZ - 1)], 1);
    __syncthreads();
    int v = tmp[t];
    for (int off = 1; off < BSZ; off <<= 1) {       // inclusive scan
        int xv = (t >= off) ? tmp[t - off] : 0;
        __syncthreads();
        tmp[t] += xv;
        __syncthreads();
    }
    int incl = tmp[t];
    int excl = incl - v;
    cur[t] = excl;
    int node = b * BSZ + t;
    if (node < N) {
        ofs[node]  = eb + excl;
        endv[node] = eb + incl;
        dinv[node] = rsqrtf((float)(v + 1));        // +1 self-loop
    }
    __syncthreads();
    for (int p = eb + t; p < ee; p += BSZ) {
        unsigned x = bins[p];
        int cl = x & (BSZ - 1);
        int l = atomicAdd(&cur[cl], 1);
        csr[eb + l] = (int)(x >> BSZ_LG);
    }
}
// =========================================================================

// ---------- layer-1 aggregation: s1[n] = dinv[n] * (xs[n] + sum_{r in nbrs} xs[r]) ----------
__global__ __launch_bounds__(256) void k_agg1(
        const unsigned short* __restrict__ xs, const int* __restrict__ csr,
        const int* __restrict__ ofs, const int* __restrict__ endv,
        const float* __restrict__ dinv, float* __restrict__ s1, int N) {
    int node = blockIdx.x * 4 + (threadIdx.x >> 6);
    if (node >= N) return;
    int lane = threadIdx.x & 63;
    int beg = ofs[node], end = endv[node];
    float acc = bf1(xs[(size_t)node * 64 + lane]);   // self term (pre-scaled)
    int p = beg;
    for (; p + 3 < end; p += 4) {
        int r0 = csr[p], r1 = csr[p + 1], r2 = csr[p + 2], r3 = csr[p + 3];
        float v0 = bf1(xs[(size_t)r0 * 64 + lane]);
        float v1 = bf1(xs[(size_t)r1 * 64 + lane]);
        float v2 = bf1(xs[(size_t)r2 * 64 + lane]);
        float v3 = bf1(xs[(size_t)r3 * 64 + lane]);
        acc += v0 + v1 + v2 + v3;
    }
    for (; p < end; ++p)
        acc += bf1(xs[(size_t)csr[p] * 64 + lane]);
    s1[(size_t)node * 64 + lane] = dinv[node] * acc;
}

// ---------- GEMM1: h1 = bf16(relu(s1 @ W1 + b1)) ----------
__global__ __launch_bounds__(256) void k_gemm1(
        const float* __restrict__ s1, const unsigned short* __restrict__ W1,
        const unsigned short* __restrict__ b1, unsigned short* __restrict__ h1, int N) {
    __shared__ __align__(16) unsigned short sW[64 * 128];  // 16KB
    __shared__ __align__(16) float sA[8 * 64];             // 2KB
    int t = threadIdx.x;
    {
        const uint2* wv = (const uint2*)W1;
        uint2* swv = (uint2*)sW;
        for (int i = t; i < 64 * 128 / 4; i += 256) swv[i] = wv[i];
    }
    int node0 = blockIdx.x * 8;
    if (node0 + 8 <= N) {
        const float4* av = (const float4*)(s1 + (size_t)node0 * 64);
        float4* sav = (float4*)sA;
        if (t < 128) sav[t] = av[t];
    } else {
        for (int i = t; i < 512; i += 256) {
            size_t g = (size_t)node0 * 64 + i;
            sA[i] = (g < (size_t)N * 64) ? s1[g] : 0.f;
        }
    }
    __syncthreads();

    int ln = t >> 5;
    int f0 = (t & 31) * 4;
    const unsigned* swu = (const unsigned*)sW;
    float a0 = 0, a1 = 0, a2 = 0, a3 = 0;
#pragma unroll 8
    for (int k = 0; k < 64; ++k) {
        float a = sA[ln * 64 + k];
        uint2 w = *(const uint2*)(swu + k * 64 + (f0 >> 1));
        a0 = fmaf(a, bf_lo(w.x), a0);
        a1 = fmaf(a, bf_hi(w.x), a1);
        a2 = fmaf(a, bf_lo(w.y), a2);
        a3 = fmaf(a, bf_hi(w.y), a3);
    }
    int node = node0 + ln;
    if (node < N) {
        float v0 = fmaxf(a0 + bf1(b1[f0 + 0]), 0.f);
        float v1 = fmaxf(a1 + bf1(b1[f0 + 1]), 0.f);
        float v2 = fmaxf(a2 + bf1(b1[f0 + 2]), 0.f);
        float v3 = fmaxf(a3 + bf1(b1[f0 + 3]), 0.f);
        uint2 o; o.x = pack2(v0, v1); o.y = pack2(v2, v3);
        *(uint2*)&h1[(size_t)node * 128 + f0] = o;
    }
}

// ---------- BN stats: 256 blocks, register accumulation, LDS reduce, sparse atomics ----------
__global__ __launch_bounds__(256) void k_bnstat(
        const unsigned short* __restrict__ h1, float* __restrict__ stats, int N) {
    __shared__ float sS[256], sQ[256];
    int t = threadIdx.x;
    int f = t & 127;
    int half = t >> 7;
    float s = 0.f, q = 0.f;
    for (int n = blockIdx.x * 2 + half; n < N; n += 512) {
        float v = bf1(h1[(size_t)n * 128 + f]);
        s += v; q = fmaf(v, v, q);
    }
    sS[t] = s; sQ[t] = q;
    __syncthreads();
    if (t < 128) {
        atomicAdd(&stats[f],       sS[t] + sS[t + 128]);
        atomicAdd(&stats[128 + f], sQ[t] + sQ[t + 128]);
    }
}

// ---------- BN finalize ----------
__global__ void k_bnfin(const float* __restrict__ stats,
                        const unsigned short* __restrict__ gamma,
                        const unsigned short* __restrict__ beta,
                        float* __restrict__ bnp, float invN) {
    int f = threadIdx.x;  // 128
    float mean = stats[f] * invN;
    float var = stats[128 + f] * invN - mean * mean;
    if (!(var >= 0.f)) var = 0.f;
    float sc = bf1(gamma[f]) * rsqrtf(var + 1e-5f);
    bnp[f] = sc;
    bnp[128 + f] = bf1(beta[f]) - mean * sc;
}

// ---------- BN apply + fold dinv ----------
__global__ __launch_bounds__(256) void k_bnapply(
        const unsigned short* __restrict__ h1, const float* __restrict__ bnp,
        const float* __restrict__ dinv, unsigned short* __restrict__ gb, int N) {
    int idx = blockIdx.x * 256 + threadIdx.x;
    if (idx >= N * 32) return;
    int n = idx >> 5;
    int f0 = (idx & 31) * 4;
    float di = dinv[n];
    uint2 h = *(const uint2*)&h1[(size_t)n * 128 + f0];
    float v0 = di * (bnp[f0 + 0] * bf_lo(h.x) + bnp[128 + f0 + 0]);
    float v1 = di * (bnp[f0 + 1] * bf_hi(h.x) + bnp[128 + f0 + 1]);
    float v2 = di * (bnp[f0 + 2] * bf_lo(h.y) + bnp[128 + f0 + 2]);
    float v3 = di * (bnp[f0 + 3] * bf_hi(h.y) + bnp[128 + f0 + 3]);
    uint2 o; o.x = pack2(v0, v1); o.y = pack2(v2, v3);
    *(uint2*)&gb[(size_t)n * 128 + f0] = o;
}

// ---------- layer-2 aggregation (128 feats) ----------
__global__ __launch_bounds__(256) void k_agg2(
        const unsigned short* __restrict__ gb, const int* __restrict__ csr,
        const int* __restrict__ ofs, const int* __restrict__ endv,
        const float* __restrict__ dinv, unsigned short* __restrict__ s2, int N) {
    int node = blockIdx.x * 4 + (threadIdx.x >> 6);
    if (node >= N) return;
    int lane = threadIdx.x & 63;
    const unsigned* g2 = (const unsigned*)gb;
    int beg = ofs[node], end = endv[node];
    float di = dinv[node];
    unsigned self = g2[(size_t)node * 64 + lane];
    float acc0 = bf_lo(self), acc1 = bf_hi(self);
    int p = beg;
    for (; p + 3 < end; p += 4) {
        int r0 = csr[p], r1 = csr[p + 1], r2 = csr[p + 2], r3 = csr[p + 3];
        unsigned u0 = g2[(size_t)r0 * 64 + lane];
        unsigned u1 = g2[(size_t)r1 * 64 + lane];
        unsigned u2 = g2[(size_t)r2 * 64 + lane];
        unsigned u3 = g2[(size_t)r3 * 64 + lane];
        acc0 += bf_lo(u0) + bf_lo(u1) + bf_lo(u2) + bf_lo(u3);
        acc1 += bf_hi(u0) + bf_hi(u1) + bf_hi(u2) + bf_hi(u3);
    }
    for (; p < end; ++p) {
        unsigned v = g2[(size_t)csr[p] * 64 + lane];
        acc0 += bf_lo(v);
        acc1 += bf_hi(v);
    }
    ((unsigned*)s2)[(size_t)node * 64 + lane] = pack2(di * acc0, di * acc1);
}

// ---------- GEMM2: out = relu(s2 @ W2 + b2); output dtype follows flagf ----------
__global__ __launch_bounds__(256) void k_gemm2(
        const unsigned short* __restrict__ s2, const unsigned short* __restrict__ W2,
        const unsigned short* __restrict__ b2, void* __restrict__ outv,
        const int* __restrict__ flagf, int N) {
    __shared__ __align__(16) unsigned short sW[128 * 128];  // 32KB
    __shared__ __align__(16) unsigned short sA[8 * 128];    // 2KB
    int t = threadIdx.x;
    {
        const uint2* wv = (const uint2*)W2;
        uint2* swv = (uint2*)sW;
        for (int i = t; i < 128 * 128 / 4; i += 256) swv[i] = wv[i];
    }
    int node0 = blockIdx.x * 8;
    if (node0 + 8 <= N) {
        const uint2* av = (const uint2*)(s2 + (size_t)node0 * 128);
        ((uint2*)sA)[t] = av[t];
    } else {
        for (int i = t; i < 1024; i += 256) {
            size_t g = (size_t)node0 * 128 + i;
            sA[i] = (g < (size_t)N * 128) ? s2[g] : 0;
        }
    }
    __syncthreads();

    int ln = t >> 5;
    int f0 = (t & 31) * 4;
    const unsigned* swu = (const unsigned*)sW;
    float a0 = 0, a1 = 0, a2 = 0, a3 = 0;
#pragma unroll 8
    for (int k = 0; k < 128; ++k) {
        float a = bf1(sA[ln * 128 + k]);
        uint2 w = *(const uint2*)(swu + k * 64 + (f0 >> 1));
        a0 = fmaf(a, bf_lo(w.x), a0);
        a1 = fmaf(a, bf_hi(w.x), a1);
        a2 = fmaf(a, bf_lo(w.y), a2);
        a3 = fmaf(a, bf_hi(w.y), a3);
    }
    int node = node0 + ln;
    if (node < N) {
        float v0 = fmaxf(a0 + bf1(b2[f0 + 0]), 0.f);
        float v1 = fmaxf(a1 + bf1(b2[f0 + 1]), 0.f);
        float v2 = fmaxf(a2 + bf1(b2[f0 + 2]), 0.f);
        float v3 = fmaxf(a3 + bf1(b2[f0 + 3]), 0.f);
        if (*flagf) {
            *(float4*)&((float*)outv)[(size_t)node * 128 + f0] = make_float4(v0, v1, v2, v3);
        } else {
            uint2 o; o.x = pack2(v0, v1); o.y = pack2(v2, v3);
            *(uint2*)&((unsigned short*)outv)[(size_t)node * 128 + f0] = o;
        }
    }
}

extern "C" void kernel_launch(void* const* d_in, const int* in_sizes, int n_in,
                              void* d_out, int out_size, void* d_ws, size_t ws_size,
                              hipStream_t stream) {
    const int N = in_sizes[0] / 64;   // 100000
    const int E = in_sizes[1] / 2;    // 1600000
    const int nW1 = in_sizes[2], nb1 = in_sizes[3], ngm = in_sizes[4],
              nbt = in_sizes[5], nW2 = in_sizes[6], nb2 = in_sizes[7];
    const int NBUCK = (N + BSZ - 1) >> BSZ_LG;     // 196 (<=256 required)

    const int* ei = (const int*)d_in[1];

    // workspace carve-up (~72 MB)
    char* w = (char*)d_ws;
    size_t off = 0;
    auto alloc = [&](size_t bytes) -> void* {
        void* p = w + off;
        off = (off + bytes + 255) & ~(size_t)255;
        return p;
    };
    int*   bcnt   = (int*)alloc(256 * 4);
    int*   bofs   = (int*)alloc(257 * 4);
    int*   bcur   = (int*)alloc(256 * 4);
    int*   flagf  = (int*)alloc(256);
    int*   flage  = (int*)alloc(256);
    int*   ofs    = (int*)alloc((size_t)N * 4);
    int*   endv   = (int*)alloc((size_t)N * 4);
    int*   csr    = (int*)alloc((size_t)E * 4);
    float* dinv   = (float*)alloc((size_t)N * 4);
    float* stats  = (float*)alloc(512 * 4);                            // sums[256] + bnp[256]
    unsigned short* xs = (unsigned short*)alloc((size_t)N * 64 * 2);   // 12.8MB
    unsigned short* wb = (unsigned short*)alloc((size_t)32768 * 2);    // params, bf16
    float* s1 = (float*)alloc((size_t)N * 64 * 4);                     // 25.6MB; also bins & gb
    unsigned short* h1 = (unsigned short*)alloc((size_t)N * 128 * 2);  // 25.6MB; reused as s2
    unsigned* bins = (unsigned*)s1;          // dead before agg1 writes s1
    unsigned short* gb = (unsigned short*)s1;
    unsigned short* s2 = h1;

    unsigned short* W1b = wb;
    unsigned short* b1b = W1b + nW1;
    unsigned short* gmb = b1b + nb1;
    unsigned short* btb = gmb + ngm;
    unsigned short* W2b = btb + nbt;
    unsigned short* b2b = W2b + nW2;

    const int NCH = (E + 4095) / 4096;   // edge chunks (391)

    k_zero   <<<1, 256, 0, stream>>>(bcnt, 256);
    k_zero   <<<1, 256, 0, stream>>>((int*)stats, 256);
    k_detectf<<<1, 256, 0, stream>>>((const unsigned*)d_in[0], flagf);
    k_detecte<<<1, 256, 0, stream>>>(ei, flage);

    k_cvt <<<(nW1 + 255) / 256, 256, 0, stream>>>(d_in[2], W1b, flagf, nW1);
    k_cvt <<<(nb1 + 255) / 256, 256, 0, stream>>>(d_in[3], b1b, flagf, nb1);
    k_cvt <<<(ngm + 255) / 256, 256, 0, stream>>>(d_in[4], gmb, flagf, ngm);
    k_cvt <<<(nbt + 255) / 256, 256, 0, stream>>>(d_in[5], btb, flagf, nbt);
    k_cvt <<<(nW2 + 255) / 256, 256, 0, stream>>>(d_in[6], W2b, flagf, nW2);
    k_cvt <<<(nb2 + 255) / 256, 256, 0, stream>>>(d_in[7], b2b, flagf, nb2);

    k_binA  <<<NCH, 256, 0, stream>>>(ei, flage, bcnt, E, N, NBUCK);
    k_bscan <<<1, 256, 0, stream>>>(bcnt, bofs, bcur, NBUCK);
    k_binB  <<<NCH, 256, 0, stream>>>(ei, flage, bcur, bins, E, N, NBUCK);
    k_csr   <<<NBUCK, BSZ, 0, stream>>>(bins, bofs, csr, ofs, endv, dinv, N);

    k_prep  <<<(N * 64 + 255) / 256, 256, 0, stream>>>(d_in[0], dinv, flagf, xs, N * 64);
    k_agg1  <<<(N + 3) / 4, 256, 0, stream>>>(xs, csr, ofs, endv, dinv, s1, N);
    k_gemm1 <<<(N + 7) / 8, 256, 0, stream>>>(s1, W1b, b1b, h1, N);
    k_bnstat<<<256, 256, 0, stream>>>(h1, stats, N);
    k_bnfin <<<1, 128, 0, stream>>>(stats, gmb, btb, stats + 256, 1.0f / (float)N);
    k_bnapply<<<((size_t)N * 32 + 255) / 256, 256, 0, stream>>>(h1, stats + 256, dinv, gb, N);
    k_agg2  <<<(N + 3) / 4, 256, 0, stream>>>(gb, csr, ofs, endv, dinv, s2, N);
    k_gemm2 <<<(N + 7) / 8, 256, 0, stream>>>(s2, W2b, b2b, d_out, flagf, N);
}

// Round 6
// 405.694 us; speedup vs baseline: 2.5908x; 1.2616x over previous
//
#include <hip/hip_runtime.h>

#define BSZ_LG 9
#define BSZ 512            // nodes per destination bucket

// ---------- bf16 helpers (manual, bit-level) ----------
__device__ __forceinline__ float bf_lo(unsigned u) { return __uint_as_float(u << 16); }
__device__ __forceinline__ float bf_hi(unsigned u) { return __uint_as_float(u & 0xffff0000u); }
__device__ __forceinline__ float bf1(unsigned short s) { return __uint_as_float(((unsigned)s) << 16); }
__device__ __forceinline__ unsigned short f2bf(float f) {
    unsigned u = __float_as_uint(f);
    u += 0x7fffu + ((u >> 16) & 1u);   // round-to-nearest-even
    return (unsigned short)(u >> 16);
}
__device__ __forceinline__ unsigned pack2(float a, float b) {
    return (unsigned)f2bf(a) | ((unsigned)f2bf(b) << 16);
}

// ---------- zeroing ----------
__global__ void k_zero(int* __restrict__ p, int n) {
    int i = blockIdx.x * 256 + threadIdx.x;
    if (i < n) p[i] = 0;
}

// ---------- detect float dtype of x ----------
__global__ void k_detectf(const unsigned* __restrict__ x, int* __restrict__ flag) {
    int t = threadIdx.x;
    int c = 0;
    for (int i = t; i < 1024; i += 256) {
        unsigned e = (x[i] >> 23) & 0xffu;
        if (e >= 96u && e < 160u) c++;
    }
    __shared__ int s;
    if (t == 0) s = 0;
    __syncthreads();
    atomicAdd(&s, c);
    __syncthreads();
    if (t == 0) *flag = (s > 512) ? 1 : 0;
}

// ---------- detect edge_index width ----------
__global__ void k_detecte(const int* __restrict__ ei, int* __restrict__ flag) {
    int t = threadIdx.x;
    int nz = 0;
    for (int i = t; i < 2048; i += 256) nz |= ei[2 * i + 1];
    __shared__ int s;
    if (t == 0) s = 0;
    __syncthreads();
    if (nz) atomicOr(&s, 1);
    __syncthreads();
    if (t == 0) *flag = (s == 0) ? 1 : 0;
}

// ---------- dtype-normalizing copy ----------
__global__ void k_cvt(const void* __restrict__ in, unsigned short* __restrict__ out,
                      const int* __restrict__ flagf, int n) {
    int i = blockIdx.x * 256 + threadIdx.x;
    if (i >= n) return;
    if (*flagf) out[i] = f2bf(((const float*)in)[i]);
    else        out[i] = ((const unsigned short*)in)[i];
}

// ---------- x prep: xs[n][f] = bf16(dinv[n] * x[n][f]) ----------
__global__ __launch_bounds__(256) void k_prep(
        const void* __restrict__ x, const float* __restrict__ dinv,
        const int* __restrict__ flagf, unsigned short* __restrict__ xs, int NF) {
    int i = blockIdx.x * 256 + threadIdx.x;
    if (i >= NF) return;
    int n = i >> 6;
    float v = *flagf ? ((const float*)x)[i] : bf1(((const unsigned short*)x)[i]);
    xs[i] = f2bf(dinv[n] * v);
}

// ================= bucketed CSR build =================
__global__ __launch_bounds__(256) void k_binA(
        const int* __restrict__ ei, const int* __restrict__ flage,
        int* __restrict__ bcnt, int E, int N, int NBUCK) {
    __shared__ int hist[256];
    int t = threadIdx.x;
    hist[t] = 0;
    __syncthreads();
    int st = *flage + 1;
    int base = blockIdx.x * 4096 + t;
#pragma unroll
    for (int i = 0; i < 16; ++i) {
        int e = base + i * 256;
        if (e < E) {
            int r = ei[(size_t)st * e];
            int c = ei[(size_t)st * (E + e)];
            if ((unsigned)r < (unsigned)N && (unsigned)c < (unsigned)N)
                atomicAdd(&hist[c >> BSZ_LG], 1);
        }
    }
    __syncthreads();
    if (t < NBUCK && hist[t] > 0) atomicAdd(&bcnt[t], hist[t]);
}

__global__ void k_bscan(const int* __restrict__ bcnt, int* __restrict__ bofs,
                        int* __restrict__ bcur, int NBUCK) {
    __shared__ int tmp[256];
    int t = threadIdx.x;
    int v = (t < NBUCK) ? bcnt[t] : 0;
    tmp[t] = v; __syncthreads();
    for (int off = 1; off < 256; off <<= 1) {
        int xv = (t >= off) ? tmp[t - off] : 0;
        __syncthreads();
        tmp[t] += xv;
        __syncthreads();
    }
    if (t < NBUCK) {
        int ex = tmp[t] - v;
        bofs[t] = ex;
        bcur[t] = ex;
        if (t == NBUCK - 1) bofs[NBUCK] = tmp[t];
    }
}

__global__ __launch_bounds__(256) void k_binB(
        const int* __restrict__ ei, const int* __restrict__ flage,
        int* __restrict__ bcur, unsigned* __restrict__ bins, int E, int N, int NBUCK) {
    __shared__ int hist[256], hincl[256], hofs[256], loc[256], gbase[256];
    __shared__ unsigned stage[4096];
    __shared__ unsigned char bseg[4096];
    int t = threadIdx.x;
    hist[t] = 0; loc[t] = 0;
    __syncthreads();
    int st = *flage + 1;
    int base = blockIdx.x * 4096 + t;
    int bs[16]; unsigned vs[16];
#pragma unroll
    for (int i = 0; i < 16; ++i) {
        int e = base + i * 256;
        bs[i] = -1; vs[i] = 0;
        if (e < E) {
            int r = ei[(size_t)st * e];
            int c = ei[(size_t)st * (E + e)];
            if ((unsigned)r < (unsigned)N && (unsigned)c < (unsigned)N) {
                bs[i] = c >> BSZ_LG;
                vs[i] = ((unsigned)r << BSZ_LG) | (unsigned)(c & (BSZ - 1));
                atomicAdd(&hist[bs[i]], 1);
            }
        }
    }
    __syncthreads();
    hincl[t] = hist[t];
    __syncthreads();
    for (int off = 1; off < 256; off <<= 1) {
        int xv = (t >= off) ? hincl[t - off] : 0;
        __syncthreads();
        hincl[t] += xv;
        __syncthreads();
    }
    hofs[t] = hincl[t] - hist[t];
    if (t < NBUCK && hist[t] > 0) gbase[t] = atomicAdd(&bcur[t], hist[t]);
    __syncthreads();
#pragma unroll
    for (int i = 0; i < 16; ++i) {
        if (bs[i] >= 0) {
            int l = atomicAdd(&loc[bs[i]], 1);
            int pos = hofs[bs[i]] + l;
            stage[pos] = vs[i];
            bseg[pos] = (unsigned char)bs[i];
        }
    }
    __syncthreads();
    int total = hincl[255];
    for (int j = t; j < total; j += 256) {
        int b = bseg[j];
        bins[gbase[b] + (j - hofs[b])] = stage[j];
    }
}

__global__ __launch_bounds__(512) void k_csr(
        const unsigned* __restrict__ bins, const int* __restrict__ bofs,
        int* __restrict__ csr, int* __restrict__ ofs, int* __restrict__ endv,
        float* __restrict__ dinv, int N) {
    __shared__ int tmp[BSZ];
    __shared__ int cur[BSZ];
    int b = blockIdx.x, t = threadIdx.x;
    int eb = bofs[b], ee = bofs[b + 1];
    tmp[t] = 0;
    __syncthreads();
    for (int p = eb + t; p < ee; p += BSZ)
        atomicAdd(&tmp[bins[p] & (BSZ - 1)], 1);
    __syncthreads();
    int v = tmp[t];
    for (int off = 1; off < BSZ; off <<= 1) {
        int xv = (t >= off) ? tmp[t - off] : 0;
        __syncthreads();
        tmp[t] += xv;
        __syncthreads();
    }
    int incl = tmp[t];
    int excl = incl - v;
    cur[t] = excl;
    int node = b * BSZ + t;
    if (node < N) {
        ofs[node]  = eb + excl;
        endv[node] = eb + incl;
        dinv[node] = rsqrtf((float)(v + 1));
    }
    __syncthreads();
    for (int p = eb + t; p < ee; p += BSZ) {
        unsigned x = bins[p];
        int cl = x & (BSZ - 1);
        int l = atomicAdd(&cur[cl], 1);
        csr[eb + l] = (int)(x >> BSZ_LG);
    }
}
// ======================================================

// ---------- layer-1 aggregation -> bf16 s1 ----------
__global__ __launch_bounds__(256) void k_agg1(
        const unsigned short* __restrict__ xs, const int* __restrict__ csr,
        const int* __restrict__ ofs, const int* __restrict__ endv,
        const float* __restrict__ dinv, unsigned short* __restrict__ s1, int N) {
    int node = blockIdx.x * 4 + (threadIdx.x >> 6);
    if (node >= N) return;
    int lane = threadIdx.x & 63;
    int beg = ofs[node], end = endv[node];
    float acc = bf1(xs[(size_t)node * 64 + lane]);
    int p = beg;
    for (; p + 3 < end; p += 4) {
        int r0 = csr[p], r1 = csr[p + 1], r2 = csr[p + 2], r3 = csr[p + 3];
        float v0 = bf1(xs[(size_t)r0 * 64 + lane]);
        float v1 = bf1(xs[(size_t)r1 * 64 + lane]);
        float v2 = bf1(xs[(size_t)r2 * 64 + lane]);
        float v3 = bf1(xs[(size_t)r3 * 64 + lane]);
        acc += v0 + v1 + v2 + v3;
    }
    for (; p < end; ++p)
        acc += bf1(xs[(size_t)csr[p] * 64 + lane]);
    s1[(size_t)node * 64 + lane] = f2bf(dinv[node] * acc);
}

// ---------- MFMA GEMM: out[M,128] = relu(A[M,K] @ W[K,128] + b) ----------
// 64-node M-tile/block, 4 waves x (16 rows x 128 cols), v_mfma_f32_16x16x32_bf16.
typedef __attribute__((ext_vector_type(8))) short bf16x8;
typedef __attribute__((ext_vector_type(4))) float f32x4;

template<int K, int OUTMODE>   // OUTMODE 0: bf16 out; 1: fp32/bf16 per flagf
__global__ __launch_bounds__(256) void k_mgemm(
        const unsigned short* __restrict__ A, const unsigned short* __restrict__ Wg,
        const unsigned short* __restrict__ bias, void* __restrict__ outv,
        const int* __restrict__ flagf, int N) {
    constexpr int KP = K + 8;   // +8 bf16 pad: 4-bank row advance -> free 2-way conflicts
    __shared__ __align__(16) unsigned short sA[64 * KP];
    __shared__ __align__(16) unsigned short sW[128 * KP];
    int t = threadIdx.x;
    int n0 = blockIdx.x * 64;

    for (int i = t; i < K * 128; i += 256) {       // stage W transposed: sW[n][k]
        int k = i >> 7, n = i & 127;
        sW[n * KP + k] = Wg[i];
    }
    {
        constexpr int rowv = K / 8;                // uint4 per A row
        const uint4* Av = (const uint4*)A;
        for (int i = t; i < 64 * rowv; i += 256) {
            int r = i / rowv, c = i % rowv;
            int node = n0 + r;
            uint4 v = make_uint4(0u, 0u, 0u, 0u);
            if (node < N) v = Av[(size_t)node * rowv + c];
            *(uint4*)&sA[r * KP + c * 8] = v;
        }
    }
    __syncthreads();

    int lane = t & 63, wave = t >> 6, quad = lane >> 4, l16 = lane & 15;
    int mb = wave * 16;

    f32x4 acc[8];
#pragma unroll
    for (int j = 0; j < 8; ++j) acc[j] = (f32x4){0.f, 0.f, 0.f, 0.f};

#pragma unroll
    for (int k0 = 0; k0 < K; k0 += 32) {
        bf16x8 af = *(const bf16x8*)&sA[(mb + l16) * KP + k0 + quad * 8];
#pragma unroll
        for (int tn = 0; tn < 8; ++tn) {
            bf16x8 bfv = *(const bf16x8*)&sW[(tn * 16 + l16) * KP + k0 + quad * 8];
            acc[tn] = __builtin_amdgcn_mfma_f32_16x16x32_bf16(af, bfv, acc[tn], 0, 0, 0);
        }
    }

    bool f32out = (OUTMODE == 1) && (*flagf != 0);
    int nodeb = n0 + mb + quad * 4;
#pragma unroll
    for (int tn = 0; tn < 8; ++tn) {
        float bv = bf1(bias[tn * 16 + l16]);
#pragma unroll
        for (int r = 0; r < 4; ++r) {
            int node = nodeb + r;
            if (node < N) {
                float v = fmaxf(acc[tn][r] + bv, 0.f);
                if (OUTMODE == 1 && f32out)
                    ((float*)outv)[(size_t)node * 128 + tn * 16 + l16] = v;
                else
                    ((unsigned short*)outv)[(size_t)node * 128 + tn * 16 + l16] = f2bf(v);
            }
        }
    }
}

// ---------- BN stats ----------
__global__ __launch_bounds__(256) void k_bnstat(
        const unsigned short* __restrict__ h1, float* __restrict__ stats, int N) {
    __shared__ float sS[256], sQ[256];
    int t = threadIdx.x;
    int f = t & 127;
    int half = t >> 7;
    float s = 0.f, q = 0.f;
    for (int n = blockIdx.x * 2 + half; n < N; n += 512) {
        float v = bf1(h1[(size_t)n * 128 + f]);
        s += v; q = fmaf(v, v, q);
    }
    sS[t] = s; sQ[t] = q;
    __syncthreads();
    if (t < 128) {
        atomicAdd(&stats[f],       sS[t] + sS[t + 128]);
        atomicAdd(&stats[128 + f], sQ[t] + sQ[t + 128]);
    }
}

// ---------- BN finalize ----------
__global__ void k_bnfin(const float* __restrict__ stats,
                        const unsigned short* __restrict__ gamma,
                        const unsigned short* __restrict__ beta,
                        float* __restrict__ bnp, float invN) {
    int f = threadIdx.x;
    float mean = stats[f] * invN;
    float var = stats[128 + f] * invN - mean * mean;
    if (!(var >= 0.f)) var = 0.f;
    float sc = bf1(gamma[f]) * rsqrtf(var + 1e-5f);
    bnp[f] = sc;
    bnp[128 + f] = bf1(beta[f]) - mean * sc;
}

// ---------- BN apply + fold dinv ----------
__global__ __launch_bounds__(256) void k_bnapply(
        const unsigned short* __restrict__ h1, const float* __restrict__ bnp,
        const float* __restrict__ dinv, unsigned short* __restrict__ gb, int N) {
    int idx = blockIdx.x * 256 + threadIdx.x;
    if (idx >= N * 32) return;
    int n = idx >> 5;
    int f0 = (idx & 31) * 4;
    float di = dinv[n];
    uint2 h = *(const uint2*)&h1[(size_t)n * 128 + f0];
    float v0 = di * (bnp[f0 + 0] * bf_lo(h.x) + bnp[128 + f0 + 0]);
    float v1 = di * (bnp[f0 + 1] * bf_hi(h.x) + bnp[128 + f0 + 1]);
    float v2 = di * (bnp[f0 + 2] * bf_lo(h.y) + bnp[128 + f0 + 2]);
    float v3 = di * (bnp[f0 + 3] * bf_hi(h.y) + bnp[128 + f0 + 3]);
    uint2 o; o.x = pack2(v0, v1); o.y = pack2(v2, v3);
    *(uint2*)&gb[(size_t)n * 128 + f0] = o;
}

// ---------- layer-2 aggregation (128 feats) ----------
__global__ __launch_bounds__(256) void k_agg2(
        const unsigned short* __restrict__ gb, const int* __restrict__ csr,
        const int* __restrict__ ofs, const int* __restrict__ endv,
        const float* __restrict__ dinv, unsigned short* __restrict__ s2, int N) {
    int node = blockIdx.x * 4 + (threadIdx.x >> 6);
    if (node >= N) return;
    int lane = threadIdx.x & 63;
    const unsigned* g2 = (const unsigned*)gb;
    int beg = ofs[node], end = endv[node];
    float di = dinv[node];
    unsigned self = g2[(size_t)node * 64 + lane];
    float acc0 = bf_lo(self), acc1 = bf_hi(self);
    int p = beg;
    for (; p + 3 < end; p += 4) {
        int r0 = csr[p], r1 = csr[p + 1], r2 = csr[p + 2], r3 = csr[p + 3];
        unsigned u0 = g2[(size_t)r0 * 64 + lane];
        unsigned u1 = g2[(size_t)r1 * 64 + lane];
        unsigned u2 = g2[(size_t)r2 * 64 + lane];
        unsigned u3 = g2[(size_t)r3 * 64 + lane];
        acc0 += bf_lo(u0) + bf_lo(u1) + bf_lo(u2) + bf_lo(u3);
        acc1 += bf_hi(u0) + bf_hi(u1) + bf_hi(u2) + bf_hi(u3);
    }
    for (; p < end; ++p) {
        unsigned v = g2[(size_t)csr[p] * 64 + lane];
        acc0 += bf_lo(v);
        acc1 += bf_hi(v);
    }
    ((unsigned*)s2)[(size_t)node * 64 + lane] = pack2(di * acc0, di * acc1);
}

extern "C" void kernel_launch(void* const* d_in, const int* in_sizes, int n_in,
                              void* d_out, int out_size, void* d_ws, size_t ws_size,
                              hipStream_t stream) {
    const int N = in_sizes[0] / 64;   // 100000
    const int E = in_sizes[1] / 2;    // 1600000
    const int nW1 = in_sizes[2], nb1 = in_sizes[3], ngm = in_sizes[4],
              nbt = in_sizes[5], nW2 = in_sizes[6], nb2 = in_sizes[7];
    const int NBUCK = (N + BSZ - 1) >> BSZ_LG;     // 196

    const int* ei = (const int*)d_in[1];

    char* w = (char*)d_ws;
    size_t off = 0;
    auto alloc = [&](size_t bytes) -> void* {
        void* p = w + off;
        off = (off + bytes + 255) & ~(size_t)255;
        return p;
    };
    int*   bcnt   = (int*)alloc(256 * 4);
    int*   bofs   = (int*)alloc(257 * 4);
    int*   bcur   = (int*)alloc(256 * 4);
    int*   flagf  = (int*)alloc(256);
    int*   flage  = (int*)alloc(256);
    int*   ofs    = (int*)alloc((size_t)N * 4);
    int*   endv   = (int*)alloc((size_t)N * 4);
    int*   csr    = (int*)alloc((size_t)E * 4);
    float* dinv   = (float*)alloc((size_t)N * 4);
    float* stats  = (float*)alloc(512 * 4);
    unsigned short* xs = (unsigned short*)alloc((size_t)N * 64 * 2);   // 12.8MB
    unsigned short* wb = (unsigned short*)alloc((size_t)32768 * 2);
    char* reg1 = (char*)alloc((size_t)N * 64 * 4);      // 25.6MB: bins | s1(bf16) | gb
    char* reg2 = (char*)alloc((size_t)N * 128 * 2);     // 25.6MB: h1 | s2
    unsigned* bins = (unsigned*)reg1;
    unsigned short* s1 = (unsigned short*)reg1;         // N*64 bf16 (bins dead by then)
    unsigned short* gb = (unsigned short*)reg1;         // N*128 bf16 (s1 dead by then)
    unsigned short* h1 = (unsigned short*)reg2;
    unsigned short* s2 = (unsigned short*)reg2;

    unsigned short* W1b = wb;
    unsigned short* b1b = W1b + nW1;
    unsigned short* gmb = b1b + nb1;
    unsigned short* btb = gmb + ngm;
    unsigned short* W2b = btb + nbt;
    unsigned short* b2b = W2b + nW2;

    const int NCH = (E + 4095) / 4096;

    k_zero   <<<1, 256, 0, stream>>>(bcnt, 256);
    k_zero   <<<1, 256, 0, stream>>>((int*)stats, 256);
    k_detectf<<<1, 256, 0, stream>>>((const unsigned*)d_in[0], flagf);
    k_detecte<<<1, 256, 0, stream>>>(ei, flage);

    k_cvt <<<(nW1 + 255) / 256, 256, 0, stream>>>(d_in[2], W1b, flagf, nW1);
    k_cvt <<<(nb1 + 255) / 256, 256, 0, stream>>>(d_in[3], b1b, flagf, nb1);
    k_cvt <<<(ngm + 255) / 256, 256, 0, stream>>>(d_in[4], gmb, flagf, ngm);
    k_cvt <<<(nbt + 255) / 256, 256, 0, stream>>>(d_in[5], btb, flagf, nbt);
    k_cvt <<<(nW2 + 255) / 256, 256, 0, stream>>>(d_in[6], W2b, flagf, nW2);
    k_cvt <<<(nb2 + 255) / 256, 256, 0, stream>>>(d_in[7], b2b, flagf, nb2);

    k_binA  <<<NCH, 256, 0, stream>>>(ei, flage, bcnt, E, N, NBUCK);
    k_bscan <<<1, 256, 0, stream>>>(bcnt, bofs, bcur, NBUCK);
    k_binB  <<<NCH, 256, 0, stream>>>(ei, flage, bcur, bins, E, N, NBUCK);
    k_csr   <<<NBUCK, BSZ, 0, stream>>>(bins, bofs, csr, ofs, endv, dinv, N);

    k_prep  <<<(N * 64 + 255) / 256, 256, 0, stream>>>(d_in[0], dinv, flagf, xs, N * 64);
    k_agg1  <<<(N + 3) / 4, 256, 0, stream>>>(xs, csr, ofs, endv, dinv, s1, N);
    k_mgemm<64, 0><<<(N + 63) / 64, 256, 0, stream>>>(s1, W1b, b1b, h1, flagf, N);
    k_bnstat<<<256, 256, 0, stream>>>(h1, stats, N);
    k_bnfin <<<1, 128, 0, stream>>>(stats, gmb, btb, stats + 256, 1.0f / (float)N);
    k_bnapply<<<((size_t)N * 32 + 255) / 256, 256, 0, stream>>>(h1, stats + 256, dinv, gb, N);
    k_agg2  <<<(N + 3) / 4, 256, 0, stream>>>(gb, csr, ofs, endv, dinv, s2, N);
    k_mgemm<128, 1><<<(N + 63) / 64, 256, 0, stream>>>(s2, W2b, b2b, d_out, flagf, N);
}

// Round 7
// 315.359 us; speedup vs baseline: 3.3329x; 1.2865x over previous
//
#include <hip/hip_runtime.h>

#define BSZ_LG 9
#define BSZ 512            // nodes per destination bucket

// ---------- bf16 helpers ----------
__device__ __forceinline__ float bf_lo(unsigned u) { return __uint_as_float(u << 16); }
__device__ __forceinline__ float bf_hi(unsigned u) { return __uint_as_float(u & 0xffff0000u); }
__device__ __forceinline__ float bf1(unsigned short s) { return __uint_as_float(((unsigned)s) << 16); }
__device__ __forceinline__ unsigned short f2bf(float f) {
    unsigned u = __float_as_uint(f);
    u += 0x7fffu + ((u >> 16) & 1u);   // round-to-nearest-even
    return (unsigned short)(u >> 16);
}
__device__ __forceinline__ unsigned pack2(float a, float b) {
    return (unsigned)f2bf(a) | ((unsigned)f2bf(b) << 16);
}

// ---------- merged setup: flags + zeroing (1 launch, 4 blocks) ----------
__global__ void k_flags(const unsigned* __restrict__ x, const int* __restrict__ ei,
                        int* __restrict__ flagf, int* __restrict__ flage,
                        int* __restrict__ bcnt, int* __restrict__ stats) {
    int t = threadIdx.x;
    if (blockIdx.x == 0) {
        int c = 0;
        for (int i = t; i < 1024; i += 256) {
            unsigned e = (x[i] >> 23) & 0xffu;
            if (e >= 96u && e < 160u) c++;
        }
        __shared__ int s;
        if (t == 0) s = 0;
        __syncthreads();
        atomicAdd(&s, c);
        __syncthreads();
        if (t == 0) *flagf = (s > 512) ? 1 : 0;
    } else if (blockIdx.x == 1) {
        int nz = 0;
        for (int i = t; i < 2048; i += 256) nz |= ei[2 * i + 1];
        __shared__ int s2;
        if (t == 0) s2 = 0;
        __syncthreads();
        if (nz) atomicOr(&s2, 1);
        __syncthreads();
        if (t == 0) *flage = (s2 == 0) ? 1 : 0;
    } else if (blockIdx.x == 2) {
        bcnt[t] = 0;
    } else {
        stats[t] = 0;
    }
}

// ---------- merged param convert (1 launch) ----------
struct Cvt6 {
    const void* src[6];
    unsigned short* dst[6];
    int off[7];   // prefix sums, off[6] = total
};
__global__ void k_cvt6(Cvt6 a, const int* __restrict__ flagf) {
    int i = blockIdx.x * 256 + threadIdx.x;
    if (i >= a.off[6]) return;
    int s = 0;
#pragma unroll
    for (int j = 1; j < 6; ++j) if (i >= a.off[j]) s = j;
    int k = i - a.off[s];
    unsigned short v;
    if (*flagf) v = f2bf(((const float*)a.src[s])[k]);
    else        v = ((const unsigned short*)a.src[s])[k];
    a.dst[s][k] = v;
}

// ---------- x prep: xs[n][f] = bf16(dinv[n]*x[n][f]), 4 feats/thread ----------
__global__ __launch_bounds__(256) void k_prep(
        const void* __restrict__ x, const float* __restrict__ dinv,
        const int* __restrict__ flagf, unsigned* __restrict__ xs32, int Nq) {
    int i = blockIdx.x * 256 + threadIdx.x;   // one per 4 feats; Nq = N*16
    if (i >= Nq) return;
    int n = i >> 4;
    float di = dinv[n];
    float v0, v1, v2, v3;
    if (*flagf) {
        float4 f = ((const float4*)x)[i];
        v0 = f.x; v1 = f.y; v2 = f.z; v3 = f.w;
    } else {
        uint2 u = ((const uint2*)x)[i];
        v0 = bf_lo(u.x); v1 = bf_hi(u.x); v2 = bf_lo(u.y); v3 = bf_hi(u.y);
    }
    uint2 o; o.x = pack2(di * v0, di * v1); o.y = pack2(di * v2, di * v3);
    ((uint2*)xs32)[i] = o;
}

// ================= bucketed CSR build =================
__global__ __launch_bounds__(256) void k_binA(
        const int* __restrict__ ei, const int* __restrict__ flage,
        int* __restrict__ bcnt, int E, int N, int NBUCK) {
    __shared__ int hist[256];
    int t = threadIdx.x;
    hist[t] = 0;
    __syncthreads();
    int st = *flage + 1;
    int base = blockIdx.x * 4096 + t;
#pragma unroll
    for (int i = 0; i < 16; ++i) {
        int e = base + i * 256;
        if (e < E) {
            int r = ei[(size_t)st * e];
            int c = ei[(size_t)st * (E + e)];
            if ((unsigned)r < (unsigned)N && (unsigned)c < (unsigned)N)
                atomicAdd(&hist[c >> BSZ_LG], 1);
        }
    }
    __syncthreads();
    if (t < NBUCK && hist[t] > 0) atomicAdd(&bcnt[t], hist[t]);
}

__global__ void k_bscan(const int* __restrict__ bcnt, int* __restrict__ bofs,
                        int* __restrict__ bcur, int NBUCK) {
    __shared__ int tmp[256];
    int t = threadIdx.x;
    int v = (t < NBUCK) ? bcnt[t] : 0;
    tmp[t] = v; __syncthreads();
    for (int off = 1; off < 256; off <<= 1) {
        int xv = (t >= off) ? tmp[t - off] : 0;
        __syncthreads();
        tmp[t] += xv;
        __syncthreads();
    }
    if (t < NBUCK) {
        int ex = tmp[t] - v;
        bofs[t] = ex;
        bcur[t] = ex;
        if (t == NBUCK - 1) bofs[NBUCK] = tmp[t];
    }
}

__global__ __launch_bounds__(256) void k_binB(
        const int* __restrict__ ei, const int* __restrict__ flage,
        int* __restrict__ bcur, unsigned* __restrict__ bins, int E, int N, int NBUCK) {
    __shared__ int hist[256], hincl[256], hofs[256], loc[256], gbase[256];
    __shared__ unsigned stage[4096];
    __shared__ unsigned char bseg[4096];
    int t = threadIdx.x;
    hist[t] = 0; loc[t] = 0;
    __syncthreads();
    int st = *flage + 1;
    int base = blockIdx.x * 4096 + t;
    int bs[16]; unsigned vs[16];
#pragma unroll
    for (int i = 0; i < 16; ++i) {
        int e = base + i * 256;
        bs[i] = -1; vs[i] = 0;
        if (e < E) {
            int r = ei[(size_t)st * e];
            int c = ei[(size_t)st * (E + e)];
            if ((unsigned)r < (unsigned)N && (unsigned)c < (unsigned)N) {
                bs[i] = c >> BSZ_LG;
                vs[i] = ((unsigned)r << BSZ_LG) | (unsigned)(c & (BSZ - 1));
                atomicAdd(&hist[bs[i]], 1);
            }
        }
    }
    __syncthreads();
    hincl[t] = hist[t];
    __syncthreads();
    for (int off = 1; off < 256; off <<= 1) {
        int xv = (t >= off) ? hincl[t - off] : 0;
        __syncthreads();
        hincl[t] += xv;
        __syncthreads();
    }
    hofs[t] = hincl[t] - hist[t];
    if (t < NBUCK && hist[t] > 0) gbase[t] = atomicAdd(&bcur[t], hist[t]);
    __syncthreads();
#pragma unroll
    for (int i = 0; i < 16; ++i) {
        if (bs[i] >= 0) {
            int l = atomicAdd(&loc[bs[i]], 1);
            int pos = hofs[bs[i]] + l;
            stage[pos] = vs[i];
            bseg[pos] = (unsigned char)bs[i];
        }
    }
    __syncthreads();
    int total = hincl[255];
    for (int j = t; j < total; j += 256) {
        int b = bseg[j];
        bins[gbase[b] + (j - hofs[b])] = stage[j];
    }
}

__global__ __launch_bounds__(512) void k_csr(
        const unsigned* __restrict__ bins, const int* __restrict__ bofs,
        int* __restrict__ csr, int* __restrict__ ofs, int* __restrict__ endv,
        float* __restrict__ dinv, int N) {
    __shared__ int tmp[BSZ];
    __shared__ int cur[BSZ];
    int b = blockIdx.x, t = threadIdx.x;
    int eb = bofs[b], ee = bofs[b + 1];
    tmp[t] = 0;
    __syncthreads();
    for (int p = eb + t; p < ee; p += BSZ)
        atomicAdd(&tmp[bins[p] & (BSZ - 1)], 1);
    __syncthreads();
    int v = tmp[t];
    for (int off = 1; off < BSZ; off <<= 1) {
        int xv = (t >= off) ? tmp[t - off] : 0;
        __syncthreads();
        tmp[t] += xv;
        __syncthreads();
    }
    int incl = tmp[t];
    int excl = incl - v;
    cur[t] = excl;
    int node = b * BSZ + t;
    if (node < N) {
        ofs[node]  = eb + excl;
        endv[node] = eb + incl;
        dinv[node] = rsqrtf((float)(v + 1));
    }
    __syncthreads();
    for (int p = eb + t; p < ee; p += BSZ) {
        unsigned x = bins[p];
        int cl = x & (BSZ - 1);
        int l = atomicAdd(&cur[cl], 1);
        csr[eb + l] = (int)(x >> BSZ_LG);
    }
}
// ======================================================

// ---------- layer-1 aggregation: half-wave per node, uint loads, 8-deep ----------
__global__ __launch_bounds__(256) void k_agg1(
        const unsigned* __restrict__ xs32, const int* __restrict__ csr,
        const int* __restrict__ ofs, const int* __restrict__ endv,
        const float* __restrict__ dinv, unsigned* __restrict__ s1_32, int N) {
    int sub = threadIdx.x >> 5, lane = threadIdx.x & 31;
    int node = blockIdx.x * 8 + sub;
    if (node >= N) return;
    int beg = ofs[node], end = endv[node];
    unsigned self = xs32[(size_t)node * 32 + lane];
    float a0 = bf_lo(self), a1 = bf_hi(self);
    int p = beg;
    for (; p + 7 < end; p += 8) {
        int r0 = csr[p], r1 = csr[p+1], r2 = csr[p+2], r3 = csr[p+3];
        int r4 = csr[p+4], r5 = csr[p+5], r6 = csr[p+6], r7 = csr[p+7];
        unsigned u0 = xs32[(size_t)r0 * 32 + lane];
        unsigned u1 = xs32[(size_t)r1 * 32 + lane];
        unsigned u2 = xs32[(size_t)r2 * 32 + lane];
        unsigned u3 = xs32[(size_t)r3 * 32 + lane];
        unsigned u4 = xs32[(size_t)r4 * 32 + lane];
        unsigned u5 = xs32[(size_t)r5 * 32 + lane];
        unsigned u6 = xs32[(size_t)r6 * 32 + lane];
        unsigned u7 = xs32[(size_t)r7 * 32 + lane];
        a0 += bf_lo(u0) + bf_lo(u1) + bf_lo(u2) + bf_lo(u3)
            + bf_lo(u4) + bf_lo(u5) + bf_lo(u6) + bf_lo(u7);
        a1 += bf_hi(u0) + bf_hi(u1) + bf_hi(u2) + bf_hi(u3)
            + bf_hi(u4) + bf_hi(u5) + bf_hi(u6) + bf_hi(u7);
    }
    for (; p + 3 < end; p += 4) {
        int r0 = csr[p], r1 = csr[p+1], r2 = csr[p+2], r3 = csr[p+3];
        unsigned u0 = xs32[(size_t)r0 * 32 + lane];
        unsigned u1 = xs32[(size_t)r1 * 32 + lane];
        unsigned u2 = xs32[(size_t)r2 * 32 + lane];
        unsigned u3 = xs32[(size_t)r3 * 32 + lane];
        a0 += bf_lo(u0) + bf_lo(u1) + bf_lo(u2) + bf_lo(u3);
        a1 += bf_hi(u0) + bf_hi(u1) + bf_hi(u2) + bf_hi(u3);
    }
    for (; p < end; ++p) {
        unsigned u = xs32[(size_t)csr[p] * 32 + lane];
        a0 += bf_lo(u); a1 += bf_hi(u);
    }
    float di = dinv[node];
    s1_32[(size_t)node * 32 + lane] = pack2(di * a0, di * a1);
}

// ---------- MFMA GEMM ----------
typedef __attribute__((ext_vector_type(8))) short bf16x8;
typedef __attribute__((ext_vector_type(4))) float f32x4;

template<int K, int OUTMODE>   // OUTMODE 0: bf16 out; 1: fp32/bf16 per flagf
__global__ __launch_bounds__(256) void k_mgemm(
        const unsigned short* __restrict__ A, const unsigned short* __restrict__ Wg,
        const unsigned short* __restrict__ bias, void* __restrict__ outv,
        const int* __restrict__ flagf, int N) {
    constexpr int KP = K + 8;
    __shared__ __align__(16) unsigned short sA[64 * KP];
    __shared__ __align__(16) unsigned short sW[128 * KP];
    int t = threadIdx.x;
    int n0 = blockIdx.x * 64;

    for (int i = t; i < K * 128; i += 256) {       // stage W transposed: sW[n][k]
        int k = i >> 7, n = i & 127;
        sW[n * KP + k] = Wg[i];
    }
    {
        constexpr int rowv = K / 8;
        const uint4* Av = (const uint4*)A;
        for (int i = t; i < 64 * rowv; i += 256) {
            int r = i / rowv, c = i % rowv;
            int node = n0 + r;
            uint4 v = make_uint4(0u, 0u, 0u, 0u);
            if (node < N) v = Av[(size_t)node * rowv + c];
            *(uint4*)&sA[r * KP + c * 8] = v;
        }
    }
    __syncthreads();

    int lane = t & 63, wave = t >> 6, quad = lane >> 4, l16 = lane & 15;
    int mb = wave * 16;

    f32x4 acc[8];
#pragma unroll
    for (int j = 0; j < 8; ++j) acc[j] = (f32x4){0.f, 0.f, 0.f, 0.f};

#pragma unroll
    for (int k0 = 0; k0 < K; k0 += 32) {
        bf16x8 af = *(const bf16x8*)&sA[(mb + l16) * KP + k0 + quad * 8];
#pragma unroll
        for (int tn = 0; tn < 8; ++tn) {
            bf16x8 bfv = *(const bf16x8*)&sW[(tn * 16 + l16) * KP + k0 + quad * 8];
            acc[tn] = __builtin_amdgcn_mfma_f32_16x16x32_bf16(af, bfv, acc[tn], 0, 0, 0);
        }
    }

    bool f32out = (OUTMODE == 1) && (*flagf != 0);
    int nodeb = n0 + mb + quad * 4;
#pragma unroll
    for (int tn = 0; tn < 8; ++tn) {
        float bv = bf1(bias[tn * 16 + l16]);
#pragma unroll
        for (int r = 0; r < 4; ++r) {
            int node = nodeb + r;
            if (node < N) {
                float v = fmaxf(acc[tn][r] + bv, 0.f);
                if (OUTMODE == 1 && f32out)
                    ((float*)outv)[(size_t)node * 128 + tn * 16 + l16] = v;
                else
                    ((unsigned short*)outv)[(size_t)node * 128 + tn * 16 + l16] = f2bf(v);
            }
        }
    }
}

// ---------- BN stats: uint2 loads, LDS matrix reduce ----------
__global__ __launch_bounds__(256) void k_bnstat(
        const unsigned short* __restrict__ h1, float* __restrict__ stats, int N) {
    __shared__ float sS[1024], sQ[1024];   // [8 groups][128 feats]
    int t = threadIdx.x;
    int lane = t & 31, g = t >> 5;
    int f0 = lane * 4;
    float s0=0, s1=0, s2=0, s3=0, q0=0, q1=0, q2=0, q3=0;
    const uint2* h2 = (const uint2*)h1;    // row = 32 uint2
    for (int n = blockIdx.x * 8 + g; n < N; n += 2048) {
        uint2 u = h2[(size_t)n * 32 + lane];
        float v0 = bf_lo(u.x), v1 = bf_hi(u.x), v2 = bf_lo(u.y), v3 = bf_hi(u.y);
        s0 += v0; s1 += v1; s2 += v2; s3 += v3;
        q0 = fmaf(v0, v0, q0); q1 = fmaf(v1, v1, q1);
        q2 = fmaf(v2, v2, q2); q3 = fmaf(v3, v3, q3);
    }
    sS[g * 128 + f0 + 0] = s0; sS[g * 128 + f0 + 1] = s1;
    sS[g * 128 + f0 + 2] = s2; sS[g * 128 + f0 + 3] = s3;
    sQ[g * 128 + f0 + 0] = q0; sQ[g * 128 + f0 + 1] = q1;
    sQ[g * 128 + f0 + 2] = q2; sQ[g * 128 + f0 + 3] = q3;
    __syncthreads();
    if (t < 128) {
        float ss = 0, qq = 0;
#pragma unroll
        for (int gg = 0; gg < 8; ++gg) { ss += sS[gg * 128 + t]; qq += sQ[gg * 128 + t]; }
        atomicAdd(&stats[t], ss);
        atomicAdd(&stats[128 + t], qq);
    }
}

// ---------- BN finalize ----------
__global__ void k_bnfin(const float* __restrict__ stats,
                        const unsigned short* __restrict__ gamma,
                        const unsigned short* __restrict__ beta,
                        float* __restrict__ bnp, float invN) {
    int f = threadIdx.x;
    float mean = stats[f] * invN;
    float var = stats[128 + f] * invN - mean * mean;
    if (!(var >= 0.f)) var = 0.f;
    float sc = bf1(gamma[f]) * rsqrtf(var + 1e-5f);
    bnp[f] = sc;
    bnp[128 + f] = bf1(beta[f]) - mean * sc;
}

// ---------- BN apply + fold dinv: uint4, 8 feats/thread ----------
__global__ __launch_bounds__(256) void k_bnapply(
        const unsigned short* __restrict__ h1, const float* __restrict__ bnp,
        const float* __restrict__ dinv, unsigned short* __restrict__ gb, int N) {
    int idx = blockIdx.x * 256 + threadIdx.x;   // one per 8 elements
    if (idx >= N * 16) return;
    int n = idx >> 4;
    int f0 = (idx & 15) * 8;
    float di = dinv[n];
    uint4 h = *(const uint4*)&h1[(size_t)n * 128 + f0];
    float v0 = di * (bnp[f0 + 0] * bf_lo(h.x) + bnp[128 + f0 + 0]);
    float v1 = di * (bnp[f0 + 1] * bf_hi(h.x) + bnp[128 + f0 + 1]);
    float v2 = di * (bnp[f0 + 2] * bf_lo(h.y) + bnp[128 + f0 + 2]);
    float v3 = di * (bnp[f0 + 3] * bf_hi(h.y) + bnp[128 + f0 + 3]);
    float v4 = di * (bnp[f0 + 4] * bf_lo(h.z) + bnp[128 + f0 + 4]);
    float v5 = di * (bnp[f0 + 5] * bf_hi(h.z) + bnp[128 + f0 + 5]);
    float v6 = di * (bnp[f0 + 6] * bf_lo(h.w) + bnp[128 + f0 + 6]);
    float v7 = di * (bnp[f0 + 7] * bf_hi(h.w) + bnp[128 + f0 + 7]);
    uint4 o;
    o.x = pack2(v0, v1); o.y = pack2(v2, v3);
    o.z = pack2(v4, v5); o.w = pack2(v6, v7);
    *(uint4*)&gb[(size_t)n * 128 + f0] = o;
}

// ---------- layer-2 aggregation: half-wave per node, uint2 loads, 8-deep ----------
__global__ __launch_bounds__(256) void k_agg2(
        const unsigned short* __restrict__ gb, const int* __restrict__ csr,
        const int* __restrict__ ofs, const int* __restrict__ endv,
        const float* __restrict__ dinv, unsigned short* __restrict__ s2, int N) {
    int sub = threadIdx.x >> 5, lane = threadIdx.x & 31;
    int node = blockIdx.x * 8 + sub;
    if (node >= N) return;
    const uint2* g2 = (const uint2*)gb;   // row = 32 uint2
    int beg = ofs[node], end = endv[node];
    uint2 self = g2[(size_t)node * 32 + lane];
    float a0 = bf_lo(self.x), a1 = bf_hi(self.x), a2 = bf_lo(self.y), a3 = bf_hi(self.y);
    int p = beg;
    for (; p + 7 < end; p += 8) {
        int r0 = csr[p], r1 = csr[p+1], r2 = csr[p+2], r3 = csr[p+3];
        int r4 = csr[p+4], r5 = csr[p+5], r6 = csr[p+6], r7 = csr[p+7];
        uint2 u0 = g2[(size_t)r0 * 32 + lane];
        uint2 u1 = g2[(size_t)r1 * 32 + lane];
        uint2 u2 = g2[(size_t)r2 * 32 + lane];
        uint2 u3 = g2[(size_t)r3 * 32 + lane];
        uint2 u4 = g2[(size_t)r4 * 32 + lane];
        uint2 u5 = g2[(size_t)r5 * 32 + lane];
        uint2 u6 = g2[(size_t)r6 * 32 + lane];
        uint2 u7 = g2[(size_t)r7 * 32 + lane];
        a0 += bf_lo(u0.x) + bf_lo(u1.x) + bf_lo(u2.x) + bf_lo(u3.x)
            + bf_lo(u4.x) + bf_lo(u5.x) + bf_lo(u6.x) + bf_lo(u7.x);
        a1 += bf_hi(u0.x) + bf_hi(u1.x) + bf_hi(u2.x) + bf_hi(u3.x)
            + bf_hi(u4.x) + bf_hi(u5.x) + bf_hi(u6.x) + bf_hi(u7.x);
        a2 += bf_lo(u0.y) + bf_lo(u1.y) + bf_lo(u2.y) + bf_lo(u3.y)
            + bf_lo(u4.y) + bf_lo(u5.y) + bf_lo(u6.y) + bf_lo(u7.y);
        a3 += bf_hi(u0.y) + bf_hi(u1.y) + bf_hi(u2.y) + bf_hi(u3.y)
            + bf_hi(u4.y) + bf_hi(u5.y) + bf_hi(u6.y) + bf_hi(u7.y);
    }
    for (; p + 3 < end; p += 4) {
        int r0 = csr[p], r1 = csr[p+1], r2 = csr[p+2], r3 = csr[p+3];
        uint2 u0 = g2[(size_t)r0 * 32 + lane];
        uint2 u1 = g2[(size_t)r1 * 32 + lane];
        uint2 u2 = g2[(size_t)r2 * 32 + lane];
        uint2 u3 = g2[(size_t)r3 * 32 + lane];
        a0 += bf_lo(u0.x) + bf_lo(u1.x) + bf_lo(u2.x) + bf_lo(u3.x);
        a1 += bf_hi(u0.x) + bf_hi(u1.x) + bf_hi(u2.x) + bf_hi(u3.x);
        a2 += bf_lo(u0.y) + bf_lo(u1.y) + bf_lo(u2.y) + bf_lo(u3.y);
        a3 += bf_hi(u0.y) + bf_hi(u1.y) + bf_hi(u2.y) + bf_hi(u3.y);
    }
    for (; p < end; ++p) {
        uint2 u = g2[(size_t)csr[p] * 32 + lane];
        a0 += bf_lo(u.x); a1 += bf_hi(u.x); a2 += bf_lo(u.y); a3 += bf_hi(u.y);
    }
    float di = dinv[node];
    uint2 o; o.x = pack2(di * a0, di * a1); o.y = pack2(di * a2, di * a3);
    ((uint2*)s2)[(size_t)node * 32 + lane] = o;
}

extern "C" void kernel_launch(void* const* d_in, const int* in_sizes, int n_in,
                              void* d_out, int out_size, void* d_ws, size_t ws_size,
                              hipStream_t stream) {
    const int N = in_sizes[0] / 64;   // 100000
    const int E = in_sizes[1] / 2;    // 1600000
    const int nW1 = in_sizes[2], nb1 = in_sizes[3], ngm = in_sizes[4],
              nbt = in_sizes[5], nW2 = in_sizes[6], nb2 = in_sizes[7];
    const int NBUCK = (N + BSZ - 1) >> BSZ_LG;     // 196

    const int* ei = (const int*)d_in[1];

    char* w = (char*)d_ws;
    size_t off = 0;
    auto alloc = [&](size_t bytes) -> void* {
        void* p = w + off;
        off = (off + bytes + 255) & ~(size_t)255;
        return p;
    };
    int*   bcnt   = (int*)alloc(256 * 4);
    int*   bofs   = (int*)alloc(257 * 4);
    int*   bcur   = (int*)alloc(256 * 4);
    int*   flagf  = (int*)alloc(256);
    int*   flage  = (int*)alloc(256);
    int*   ofs    = (int*)alloc((size_t)N * 4);
    int*   endv   = (int*)alloc((size_t)N * 4);
    int*   csr    = (int*)alloc((size_t)E * 4);
    float* dinv   = (float*)alloc((size_t)N * 4);
    float* stats  = (float*)alloc(512 * 4);
    unsigned* xs32 = (unsigned*)alloc((size_t)N * 64 * 2);             // 12.8MB
    unsigned short* wb = (unsigned short*)alloc((size_t)32768 * 2);
    char* reg1 = (char*)alloc((size_t)N * 64 * 4);      // bins | s1(bf16) | gb
    char* reg2 = (char*)alloc((size_t)N * 128 * 2);     // h1 | s2
    unsigned* bins = (unsigned*)reg1;
    unsigned short* s1 = (unsigned short*)reg1;
    unsigned short* gb = (unsigned short*)reg1;
    unsigned short* h1 = (unsigned short*)reg2;
    unsigned short* s2 = (unsigned short*)reg2;

    unsigned short* W1b = wb;
    unsigned short* b1b = W1b + nW1;
    unsigned short* gmb = b1b + nb1;
    unsigned short* btb = gmb + ngm;
    unsigned short* W2b = btb + nbt;
    unsigned short* b2b = W2b + nW2;

    const int NCH = (E + 4095) / 4096;

    k_flags <<<4, 256, 0, stream>>>((const unsigned*)d_in[0], ei, flagf, flage,
                                    bcnt, (int*)stats);
    Cvt6 ca;
    ca.src[0] = d_in[2]; ca.dst[0] = W1b;
    ca.src[1] = d_in[3]; ca.dst[1] = b1b;
    ca.src[2] = d_in[4]; ca.dst[2] = gmb;
    ca.src[3] = d_in[5]; ca.dst[3] = btb;
    ca.src[4] = d_in[6]; ca.dst[4] = W2b;
    ca.src[5] = d_in[7]; ca.dst[5] = b2b;
    int szs[6] = {nW1, nb1, ngm, nbt, nW2, nb2};
    ca.off[0] = 0;
    for (int i = 0; i < 6; ++i) ca.off[i + 1] = ca.off[i] + szs[i];
    k_cvt6 <<<(ca.off[6] + 255) / 256, 256, 0, stream>>>(ca, flagf);

    k_binA  <<<NCH, 256, 0, stream>>>(ei, flage, bcnt, E, N, NBUCK);
    k_bscan <<<1, 256, 0, stream>>>(bcnt, bofs, bcur, NBUCK);
    k_binB  <<<NCH, 256, 0, stream>>>(ei, flage, bcur, bins, E, N, NBUCK);
    k_csr   <<<NBUCK, BSZ, 0, stream>>>(bins, bofs, csr, ofs, endv, dinv, N);

    k_prep  <<<(N * 16 + 255) / 256, 256, 0, stream>>>(d_in[0], dinv, flagf, xs32, N * 16);
    k_agg1  <<<(N + 7) / 8, 256, 0, stream>>>(xs32, csr, ofs, endv, dinv, (unsigned*)s1, N);
    k_mgemm<64, 0><<<(N + 63) / 64, 256, 0, stream>>>(s1, W1b, b1b, h1, flagf, N);
    k_bnstat<<<256, 256, 0, stream>>>(h1, stats, N);
    k_bnfin <<<1, 128, 0, stream>>>(stats, gmb, btb, stats + 256, 1.0f / (float)N);
    k_bnapply<<<((size_t)N * 16 + 255) / 256, 256, 0, stream>>>(h1, stats + 256, dinv, gb, N);
    k_agg2  <<<(N + 7) / 8, 256, 0, stream>>>(gb, csr, ofs, endv, dinv, s2, N);
    k_mgemm<128, 1><<<(N + 63) / 64, 256, 0, stream>>>(s2, W2b, b2b, d_out, flagf, N);
}